// Round 8
// baseline (403.771 us; speedup 1.0000x reference)
//
#include <hip/hip_runtime.h>
#include <math.h>
#include <stdint.h>

using f16 = _Float16;
using half8 = __attribute__((ext_vector_type(8))) f16;
using half4 = __attribute__((ext_vector_type(4))) f16;
using f32x4 = __attribute__((ext_vector_type(4))) float;

__device__ __forceinline__ void gl_lds16(const f16* g, f16* l) {
  __builtin_amdgcn_global_load_lds(
      (const __attribute__((address_space(1))) void*)g,
      (__attribute__((address_space(3))) void*)l, 16, 0, 0);
}

// ---------------------------------------------------------------------------
// 256^2-tile Markidis GEMM, product-phase schedule with counted vmcnt (T2+T4+T5)
// Lsplit[M,N] = scale * (A.B^T hh+hm+mh over split2 planes), split2-f16 out.
// 8 waves (wave tile 128x64), KSTEP=32, double-buffered 128KB LDS.
// Per tile: 3 phases {hh: A0.B0 | hm: A0.B1 | mh: A1.B0}; next-tile staging
// issued phase-aligned {0,1,4 | 5,6,7 | 2,3}; phase-end waits vmcnt(5/6/4) —
// >=4 loads always in flight. Race-safe: stages write buf[(t+1)&1] which no
// wave reads until the tile-boundary barrier.
//   stage call c: 0,1=A-pl0  2,3=A-pl1  4,5=B-pl0  6,7=B-pl1  (512 gran each)
// ---------------------------------------------------------------------------
__global__ __launch_bounds__(512, 2) void gemm_q4(
    const f16* __restrict__ Ap, const f16* __restrict__ Bp,
    f16* __restrict__ Ch, long sCp, int N, int K, long sAp, long sBp,
    float scale) {
  // buffer (granules of 16B): [A: pl*1024 + r*4 + kg | B: 2048 + same]
  __shared__ f16 lds[2 * 4096 * 8];
  const int tid = threadIdx.x;
  const int lane = tid & 63;
  const int wave = tid >> 6;
  const int wr = (wave >> 2) * 128;
  const int wc = (wave & 3) * 64;

  const int nwg = gridDim.x * gridDim.y;
  int bid = blockIdx.y * gridDim.x + blockIdx.x;
  bid = (bid & 7) * (nwg >> 3) + (bid >> 3);  // XCD-aware (nwg % 8 == 0)
  const int bm = (bid / gridDim.x) * 256;
  const int bn = (bid % gridDim.x) * 256;

  const int nt = K / 32;

  // stage call c (0..7) of tile t: 512 granules, 1 gl_lds/thread.
  auto stage = [&](int t, int c) {
    const int g0 = c * 512 + wave * 64;  // wave-uniform granule base
    const int ga = g0 + lane;
    const bool isB = ga >= 2048;
    const int gl = ga & 2047;
    const int pl = gl >> 10;
    const int gp = gl & 1023;
    const int r = gp >> 2;
    const int cg = (gp & 3) ^ ((r >> 1) & 3);  // XOR-swizzled source granule
    const f16* gs = (isB ? Bp + (size_t)pl * sBp + (size_t)(bn + r) * K
                         : Ap + (size_t)pl * sAp + (size_t)(bm + r) * K) +
                    t * 32 + cg * 8;
    gl_lds16(gs, &lds[((size_t)(t & 1) * 4096 + g0) * 8]);
  };

  // fragment ds_read offsets (halfs within buffer), swizzled
  int aoff[2][8], boff[2][4];
#pragma unroll
  for (int pl = 0; pl < 2; ++pl) {
#pragma unroll
    for (int fr = 0; fr < 8; ++fr) {
      const int row = wr + fr * 16 + (lane & 15);
      const int kg = (lane >> 4) ^ ((row >> 1) & 3);
      aoff[pl][fr] = (pl * 1024 + row * 4 + kg) * 8;
    }
#pragma unroll
    for (int fc = 0; fc < 4; ++fc) {
      const int col = wc + fc * 16 + (lane & 15);
      const int kg = (lane >> 4) ^ ((col >> 1) & 3);
      boff[pl][fc] = (2048 + pl * 1024 + col * 4 + kg) * 8;
    }
  }

  f32x4 acc[8][4];
#pragma unroll
  for (int m = 0; m < 8; ++m)
#pragma unroll
    for (int n = 0; n < 4; ++n) acc[m][n] = (f32x4){0.f, 0.f, 0.f, 0.f};

  half8 a0[8], a1[8], b0[4], b1[4];

#define RD_A(dst, pl)                                   \
  _Pragma("unroll") for (int i = 0; i < 8; ++i) dst[i] = \
      *(const half8*)&buf[aoff[pl][i]];
#define RD_B(dst, pl)                                   \
  _Pragma("unroll") for (int j = 0; j < 4; ++j) dst[j] = \
      *(const half8*)&buf[boff[pl][j]];
#define MFMA_P(A, B)                                                        \
  _Pragma("unroll") for (int i = 0; i < 8; ++i)                             \
      _Pragma("unroll") for (int j = 0; j < 4; ++j) acc[i][j] =             \
          __builtin_amdgcn_mfma_f32_16x16x32_f16(A[i], B[j], acc[i][j], 0, \
                                                 0, 0);
#define SBAR0() __builtin_amdgcn_sched_barrier(0)

  // prologue: tile 0 issued in phase-aligned order; boundary wait matches
  // steady state (outstanding 4 after vmcnt(4)).
  stage(0, 0); stage(0, 1); stage(0, 4); stage(0, 5);
  stage(0, 6); stage(0, 7); stage(0, 2); stage(0, 3);
  asm volatile("s_waitcnt vmcnt(4)" ::: "memory");
  asm volatile("s_barrier" ::: "memory");

  for (int t = 0; t < nt; ++t) {
    const f16* buf = &lds[(size_t)(t & 1) * 4096 * 8];
    const bool pf = (t + 1 < nt);

    // ---- phase 1: hh  (A-pl0 . B-pl0)
    RD_A(a0, 0);
    RD_B(b0, 0);
    if (pf) { stage(t + 1, 0); stage(t + 1, 1); stage(t + 1, 4); }
    SBAR0();
    asm volatile("s_waitcnt lgkmcnt(0)" ::: "memory");
    SBAR0();
    __builtin_amdgcn_s_setprio(1);
    MFMA_P(a0, b0);
    __builtin_amdgcn_s_setprio(0);
    SBAR0();
    if (pf)
      asm volatile("s_waitcnt vmcnt(5)" ::: "memory");  // t's B-pl1 landed
    else
      asm volatile("s_waitcnt vmcnt(2)" ::: "memory");
    asm volatile("s_barrier" ::: "memory");

    // ---- phase 2: hm  (A-pl0 . B-pl1)
    RD_B(b1, 1);
    if (pf) { stage(t + 1, 5); stage(t + 1, 6); stage(t + 1, 7); }
    SBAR0();
    asm volatile("s_waitcnt lgkmcnt(0)" ::: "memory");
    SBAR0();
    __builtin_amdgcn_s_setprio(1);
    MFMA_P(a0, b1);
    __builtin_amdgcn_s_setprio(0);
    SBAR0();
    if (pf)
      asm volatile("s_waitcnt vmcnt(6)" ::: "memory");  // t's A-pl1 landed
    else
      asm volatile("s_waitcnt vmcnt(0)" ::: "memory");
    asm volatile("s_barrier" ::: "memory");

    // ---- phase 3: mh  (A-pl1 . B-pl0 re-read)
    RD_A(a1, 1);
    RD_B(b0, 0);
    if (pf) { stage(t + 1, 2); stage(t + 1, 3); }
    SBAR0();
    asm volatile("s_waitcnt lgkmcnt(0)" ::: "memory");
    SBAR0();
    __builtin_amdgcn_s_setprio(1);
    MFMA_P(a1, b0);
    __builtin_amdgcn_s_setprio(0);
    SBAR0();
    if (pf)
      asm volatile("s_waitcnt vmcnt(4)" ::: "memory");  // t+1's A0,B0 landed
    asm volatile("s_barrier" ::: "memory");  // tile boundary
  }
#undef RD_A
#undef RD_B
#undef MFMA_P
#undef SBAR0

  // epilogue: split2-f16 planes. C/D layout: col = lane&15, row = (lane>>4)*4+q
#pragma unroll
  for (int m = 0; m < 8; ++m) {
#pragma unroll
    for (int n = 0; n < 4; ++n) {
      const int col = bn + wc + n * 16 + (lane & 15);
#pragma unroll
      for (int q = 0; q < 4; ++q) {
        const int row = bm + wr + m * 16 + (lane >> 4) * 4 + q;
        const float v = acc[m][n][q] * scale;
        const f16 h = (f16)v;
        Ch[(size_t)row * N + col] = h;
        Ch[sCp + (size_t)row * N + col] = (f16)(v - (float)h);
      }
    }
  }
}

// ---------------------------------------------------------------------------
// 128^2 deep-pipelined GEMM (round 4), used for G2/G3/G5.
// ---------------------------------------------------------------------------
template <int NP, int EPI, bool BIASF>
__global__ __launch_bounds__(512, 2) void gemm_dp(
    const f16* __restrict__ Ap, const f16* __restrict__ Bp,
    void* __restrict__ Cv, const float* __restrict__ bias, int M, int N, int K,
    long sAp, long sBp, long sCp, float scale) {
  __shared__ f16 lds[3 * 2048 * 8];
  const int tid = threadIdx.x;
  const int lane = tid & 63;
  const int wave = tid >> 6;
  const int wr = (wave >> 1) * 32;
  const int wc = (wave & 1) * 64;

  const int nwg = gridDim.x * gridDim.y;
  int bid = blockIdx.y * gridDim.x + blockIdx.x;
  bid = (bid & 7) * (nwg >> 3) + (bid >> 3);
  const int bm = (bid / gridDim.x) * 128;
  const int bn = (bid % gridDim.x) * 128;

  constexpr int KSTEP = (NP == 2) ? 32 : 64;
  const int nt = K / KSTEP;

  auto stage = [&](int t, int i) {
    const int g0 = i * 512 + wave * 64;
    const int ga = g0 + lane;
    const bool isB = ga >= 1024;
    const int gl = ga & 1023;
    const int pl = gl >> 9;
    const int gp = gl & 511;
    const int r = gp >> 2;
    const int cg = (gp & 3) ^ ((r >> 1) & 3);
    const long sP = (NP == 2) ? (isB ? sBp : sAp) : 0;
    const int kOff = (NP == 2) ? 0 : pl * 32;
    const f16* gs = (isB ? Bp : Ap) + (size_t)pl * sP +
                    (size_t)((isB ? bn : bm) + r) * K + t * KSTEP + kOff +
                    cg * 8;
    gl_lds16(gs, &lds[((size_t)(t % 3) * 2048 + g0) * 8]);
  };

  int aoff[2][2], boff[2][4];
#pragma unroll
  for (int pl = 0; pl < 2; ++pl) {
#pragma unroll
    for (int m = 0; m < 2; ++m) {
      const int row = wr + m * 16 + (lane & 15);
      const int kg = (lane >> 4) ^ ((row >> 1) & 3);
      aoff[pl][m] = (pl * 512 + row * 4 + kg) * 8;
    }
#pragma unroll
    for (int n = 0; n < 4; ++n) {
      const int col = wc + n * 16 + (lane & 15);
      const int kg = (lane >> 4) ^ ((col >> 1) & 3);
      boff[pl][n] = (1024 + pl * 512 + col * 4 + kg) * 8;
    }
  }

  f32x4 acc[2][4];
#pragma unroll
  for (int m = 0; m < 2; ++m)
#pragma unroll
    for (int n = 0; n < 4; ++n) acc[m][n] = (f32x4){0.f, 0.f, 0.f, 0.f};

#pragma unroll
  for (int i = 0; i < 4; ++i) stage(0, i);
#pragma unroll
  for (int i = 0; i < 4; ++i) stage(1, i);

  for (int t = 0; t < nt; ++t) {
    const f16* buf = &lds[(size_t)(t % 3) * 2048 * 8];
    if (t + 1 < nt)
      asm volatile("s_waitcnt vmcnt(4)" ::: "memory");
    else
      asm volatile("s_waitcnt vmcnt(0)" ::: "memory");
    asm volatile("s_barrier" ::: "memory");

    half8 af[2][2], b0[2][2];
#pragma unroll
    for (int pl = 0; pl < 2; ++pl) {
#pragma unroll
      for (int m = 0; m < 2; ++m) af[pl][m] = *(const half8*)&buf[aoff[pl][m]];
#pragma unroll
      for (int j = 0; j < 2; ++j) b0[pl][j] = *(const half8*)&buf[boff[pl][j]];
    }
    if (t + 2 < nt) {
      stage(t + 2, 0);
      stage(t + 2, 1);
    }
    __builtin_amdgcn_sched_barrier(0);
    asm volatile("s_barrier" ::: "memory");
    asm volatile("s_waitcnt lgkmcnt(0)" ::: "memory");
    __builtin_amdgcn_sched_barrier(0);
    __builtin_amdgcn_s_setprio(1);
#pragma unroll
    for (int m = 0; m < 2; ++m) {
#pragma unroll
      for (int j = 0; j < 2; ++j) {
        acc[m][j] = __builtin_amdgcn_mfma_f32_16x16x32_f16(af[0][m], b0[0][j],
                                                           acc[m][j], 0, 0, 0);
        if (NP == 2) {
          acc[m][j] = __builtin_amdgcn_mfma_f32_16x16x32_f16(
              af[0][m], b0[1][j], acc[m][j], 0, 0, 0);
          acc[m][j] = __builtin_amdgcn_mfma_f32_16x16x32_f16(
              af[1][m], b0[0][j], acc[m][j], 0, 0, 0);
        } else {
          acc[m][j] = __builtin_amdgcn_mfma_f32_16x16x32_f16(
              af[1][m], b0[1][j], acc[m][j], 0, 0, 0);
        }
      }
    }
    __builtin_amdgcn_s_setprio(0);
    __builtin_amdgcn_sched_barrier(0);
    asm volatile("s_barrier" ::: "memory");

    half8 b1[2][2];
#pragma unroll
    for (int pl = 0; pl < 2; ++pl)
#pragma unroll
      for (int j = 0; j < 2; ++j)
        b1[pl][j] = *(const half8*)&buf[boff[pl][2 + j]];
    if (t + 2 < nt) {
      stage(t + 2, 2);
      stage(t + 2, 3);
    }
    __builtin_amdgcn_sched_barrier(0);
    asm volatile("s_barrier" ::: "memory");
    asm volatile("s_waitcnt lgkmcnt(0)" ::: "memory");
    __builtin_amdgcn_sched_barrier(0);
    __builtin_amdgcn_s_setprio(1);
#pragma unroll
    for (int m = 0; m < 2; ++m) {
#pragma unroll
      for (int j = 0; j < 2; ++j) {
        acc[m][2 + j] = __builtin_amdgcn_mfma_f32_16x16x32_f16(
            af[0][m], b1[0][j], acc[m][2 + j], 0, 0, 0);
        if (NP == 2) {
          acc[m][2 + j] = __builtin_amdgcn_mfma_f32_16x16x32_f16(
              af[0][m], b1[1][j], acc[m][2 + j], 0, 0, 0);
          acc[m][2 + j] = __builtin_amdgcn_mfma_f32_16x16x32_f16(
              af[1][m], b1[0][j], acc[m][2 + j], 0, 0, 0);
        } else {
          acc[m][2 + j] = __builtin_amdgcn_mfma_f32_16x16x32_f16(
              af[1][m], b1[1][j], acc[m][2 + j], 0, 0, 0);
        }
      }
    }
    __builtin_amdgcn_s_setprio(0);
    __builtin_amdgcn_sched_barrier(0);
  }

#pragma unroll
  for (int m = 0; m < 2; ++m) {
#pragma unroll
    for (int n = 0; n < 4; ++n) {
      const int col = bn + wc + n * 16 + (lane & 15);
      const float bv = BIASF ? bias[col] : 0.f;
#pragma unroll
      for (int q = 0; q < 4; ++q) {
        const int row = bm + wr + m * 16 + (lane >> 4) * 4 + q;
        float v = acc[m][n][q] * scale;
        if (EPI == 0) {
          ((float*)Cv)[(size_t)row * N + col] = v + bv;
        } else if (EPI == 1) {
          f16* C = (f16*)Cv;
          const f16 h = (f16)v;
          C[(size_t)row * N + col] = h;
          C[sCp + (size_t)row * N + col] = (f16)(v - (float)h);
        } else {
          ((f16*)Cv)[(size_t)row * N + col] = (f16)v;
        }
      }
    }
  }
}

// ---------------------------------------------------------------------------
// Round-3 2-barrier kernel, kept for the tiny G1 (grid 128)
// ---------------------------------------------------------------------------
template <int NP, int TN, int EPI, bool BIASF, int MINW>
__global__ __launch_bounds__(256, MINW) void gemm_mp(
    const f16* __restrict__ Ap, const f16* __restrict__ Bp,
    void* __restrict__ Cv, const float* __restrict__ bias, int M, int N, int K,
    long sAp, long sBp, long sCp, float scale) {
  constexpr int FR = (TN == 128) ? 4 : 2;
  constexpr int FC = 4;
  constexpr int AG = NP * 512;
  constexpr int BPG = TN * 4;
  __shared__ f16 As[NP * 128 * 32];
  __shared__ f16 Bs[NP * TN * 32];
  const int tid = threadIdx.x;
  const int lane = tid & 63;
  const int wave = tid >> 6;
  const int wr = (TN == 128) ? (wave >> 1) * 64 : wave * 32;
  const int wc = (TN == 128) ? (wave & 1) * 64 : 0;

  const int nwg = gridDim.x * gridDim.y;
  int bid = blockIdx.y * gridDim.x + blockIdx.x;
  bid = (bid & 7) * (nwg >> 3) + (bid >> 3);
  const int bm = (bid / gridDim.x) * 128;
  const int bn = (bid % gridDim.x) * TN;

  int aoff[NP][FR], boff[NP][FC];
#pragma unroll
  for (int p = 0; p < NP; ++p) {
#pragma unroll
    for (int m = 0; m < FR; ++m) {
      const int row = wr + m * 16 + (lane & 15);
      const int kga = (lane >> 4) ^ ((row >> 1) & 3);
      aoff[p][m] = (p * 512 + row * 4 + kga) * 8;
    }
#pragma unroll
    for (int n = 0; n < FC; ++n) {
      const int col = wc + n * 16 + (lane & 15);
      const int kgb = (lane >> 4) ^ ((col >> 1) & 3);
      boff[p][n] = (p * BPG + col * 4 + kgb) * 8;
    }
  }

  f32x4 acc[FR][FC];
#pragma unroll
  for (int m = 0; m < FR; ++m)
#pragma unroll
    for (int n = 0; n < FC; ++n) acc[m][n] = (f32x4){0.f, 0.f, 0.f, 0.f};

  for (int k0 = 0; k0 < K; k0 += 32) {
#pragma unroll
    for (int i = 0; i < (NP * (512 + TN * 4)) / 256; ++i) {
      const int g0 = i * 256 + wave * 64;
      const bool isB = g0 >= AG;
      const int ga0 = g0 - (isB ? AG : 0);
      const int ga = ga0 + lane;
      const int pl = isB ? (ga / BPG) : (ga >> 9);
      const int gp = isB ? (ga % BPG) : (ga & 511);
      const int r = gp >> 2;
      const int cg = (gp & 3) ^ ((r >> 1) & 3);
      const f16* gs = (isB ? Bp + (size_t)pl * sBp + (size_t)(bn + r) * K
                           : Ap + (size_t)pl * sAp + (size_t)(bm + r) * K) +
                      k0 + cg * 8;
      f16* ld = (isB ? Bs : As) + (size_t)ga0 * 8;
      gl_lds16(gs, ld);
    }
    __syncthreads();

    half8 af[NP][FR], bf[NP][FC];
#pragma unroll
    for (int p = 0; p < NP; ++p) {
#pragma unroll
      for (int m = 0; m < FR; ++m) af[p][m] = *(const half8*)&As[aoff[p][m]];
#pragma unroll
      for (int n = 0; n < FC; ++n) bf[p][n] = *(const half8*)&Bs[boff[p][n]];
    }
#pragma unroll
    for (int m = 0; m < FR; ++m) {
#pragma unroll
      for (int n = 0; n < FC; ++n) {
        acc[m][n] = __builtin_amdgcn_mfma_f32_16x16x32_f16(af[0][m], bf[0][n],
                                                           acc[m][n], 0, 0, 0);
        if (NP == 2) {
          acc[m][n] = __builtin_amdgcn_mfma_f32_16x16x32_f16(
              af[0][m], bf[1][n], acc[m][n], 0, 0, 0);
          acc[m][n] = __builtin_amdgcn_mfma_f32_16x16x32_f16(
              af[1][m], bf[0][n], acc[m][n], 0, 0, 0);
        }
      }
    }
    __syncthreads();
  }

#pragma unroll
  for (int m = 0; m < FR; ++m) {
#pragma unroll
    for (int n = 0; n < FC; ++n) {
      const int col = bn + wc + n * 16 + (lane & 15);
      const float bv = BIASF ? bias[col] : 0.f;
#pragma unroll
      for (int q = 0; q < 4; ++q) {
        const int row = bm + wr + m * 16 + (lane >> 4) * 4 + q;
        float v = acc[m][n][q] * scale;
        if (EPI == 0) {
          ((float*)Cv)[(size_t)row * N + col] = v + bv;
        } else if (EPI == 1) {
          f16* C = (f16*)Cv;
          const f16 h = (f16)v;
          C[(size_t)row * N + col] = h;
          C[sCp + (size_t)row * N + col] = (f16)(v - (float)h);
        } else {
          ((f16*)Cv)[(size_t)row * N + col] = (f16)v;
        }
      }
    }
  }
}

// fused elementwise splits: X->split2, R->split2, W->split1 (one launch)
__global__ __launch_bounds__(256) void split_fused(
    const float* __restrict__ X, const float* __restrict__ R,
    const float* __restrict__ W, f16* __restrict__ Xp, f16* __restrict__ Rp,
    f16* __restrict__ Wp, long sX, long sR) {
  const int b = blockIdx.x;
  const float* in;
  f16* out;
  long ps;
  int np, i;
  if (b < 4096) {
    in = X; out = Xp; ps = sX; np = 2; i = b * 256 + threadIdx.x;
  } else if (b < 5120) {
    in = R; out = Rp; ps = sR; np = 2; i = (b - 4096) * 256 + threadIdx.x;
  } else {
    in = W; out = Wp; ps = 0; np = 1; i = (b - 5120) * 256 + threadIdx.x;
  }
  const float4 v = ((const float4*)in)[i];
  const float vv[4] = {v.x, v.y, v.z, v.w};
  half4 h, mm;
#pragma unroll
  for (int q = 0; q < 4; ++q) {
    h[q] = (f16)vv[q];
    mm[q] = (f16)(vv[q] - (float)h[q]);
  }
  ((half4*)out)[i] = h;
  if (np == 2) ((half4*)(out + ps))[i] = mm;
}

// fp32 [Mr,Nc] -> 2 fp16 planes of the TRANSPOSE [Nc,Mr]
__global__ __launch_bounds__(256) void split_t2(const float* __restrict__ in,
                                                f16* __restrict__ out, int Mr,
                                                int Nc, long planeStride) {
  __shared__ float Ls[64][65];
  const int i0 = blockIdx.y * 64;
  const int j0 = blockIdx.x * 64;
  const int t = threadIdx.x;
  const int r = t >> 4;
  const int c = (t & 15) * 4;
#pragma unroll
  for (int i = 0; i < 4; ++i) {
    const float4 v =
        *(const float4*)&in[(size_t)(i0 + r + i * 16) * Nc + j0 + c];
    Ls[r + i * 16][c + 0] = v.x;
    Ls[r + i * 16][c + 1] = v.y;
    Ls[r + i * 16][c + 2] = v.z;
    Ls[r + i * 16][c + 3] = v.w;
  }
  __syncthreads();
#pragma unroll
  for (int i = 0; i < 4; ++i) {
    const int r2 = r + i * 16;
    half4 h, mm;
#pragma unroll
    for (int q = 0; q < 4; ++q) {
      const float v = Ls[c + q][r2];
      h[q] = (f16)v;
      mm[q] = (f16)(v - (float)h[q]);
    }
    *(half4*)&out[(size_t)(j0 + r2) * Mr + i0 + c] = h;
    *(half4*)&out[planeStride + (size_t)(j0 + r2) * Mr + i0 + c] = mm;
  }
}

// row softmax over split2-f16 logits [4096] -> f16 P row; one block per row.
__global__ __launch_bounds__(256) void softmax_ps(const f16* __restrict__ Lh,
                                                  long sL,
                                                  f16* __restrict__ P) {
  __shared__ float row[4096];
  __shared__ float red[8];
  const int rix = blockIdx.x;
  const f16* ph = Lh + (size_t)rix * 4096;
  const f16* pm = ph + sL;
  f16* o = P + (size_t)rix * 4096;
  const int tid = threadIdx.x;

  float mx = -INFINITY;
  for (int i = tid * 8; i < 4096; i += 2048) {
    const half8 h = *(const half8*)&ph[i];
    const half8 mseg = *(const half8*)&pm[i];
#pragma unroll
    for (int q = 0; q < 8; ++q) {
      const float v = (float)h[q] + (float)mseg[q];
      row[i + q] = v;
      mx = fmaxf(mx, v);
    }
  }
#pragma unroll
  for (int off = 32; off > 0; off >>= 1) mx = fmaxf(mx, __shfl_xor(mx, off));
  if ((tid & 63) == 0) red[tid >> 6] = mx;
  __syncthreads();
  mx = fmaxf(fmaxf(red[0], red[1]), fmaxf(red[2], red[3]));

  float s = 0.f;
  for (int i = tid * 4; i < 4096; i += 1024) {
    float4 v = *reinterpret_cast<const float4*>(&row[i]);
    v.x = expf(v.x - mx);
    v.y = expf(v.y - mx);
    v.z = expf(v.z - mx);
    v.w = expf(v.w - mx);
    s += v.x + v.y + v.z + v.w;
    *reinterpret_cast<float4*>(&row[i]) = v;
  }
#pragma unroll
  for (int off = 32; off > 0; off >>= 1) s += __shfl_xor(s, off);
  if ((tid & 63) == 0) red[4 + (tid >> 6)] = s;
  __syncthreads();
  s = red[4] + red[5] + red[6] + red[7];
  const float inv = 1.0f / s;

  for (int i = tid * 8; i < 4096; i += 2048) {
    half8 h;
#pragma unroll
    for (int q = 0; q < 8; ++q) h[q] = (f16)(row[i + q] * inv);
    *(half8*)&o[i] = h;
  }
}

extern "C" void kernel_launch(void* const* d_in, const int* in_sizes, int n_in,
                              void* d_out, int out_size, void* d_ws,
                              size_t ws_size, hipStream_t stream) {
  const float* X = (const float*)d_in[0];   // [4096,1024]
  const float* R = (const float*)d_in[1];   // [1024,1024]
  const float* Wl = (const float*)d_in[2];  // [1024,1024] (out,in)
  const float* bias = (const float*)d_in[3];
  float* out = (float*)d_out;

  const int Bq = 4096, D = 1024;
  const size_t MiB = 1 << 20;
  uint8_t* w8 = (uint8_t*)d_ws;
  // Layout (live-range checked):
  //  Xp [0,16) split2 X           (dead after G4; Pp overwrites)
  //  Tp [16,32) split2 T          (dead after G4)
  //  Yt [32,40) f16 (X W^T)^T     (live until G5)
  //  Wp [40,42) f16 W             (dead after G3)
  //  Rp [42,46) Rtp [46,50) Mtp [50,54)  (dead after G2)
  //  Lh [54,70) Lm [70,86) split2 logits (dead after softmax)
  //  Pp [0,32)  f16 P             (written by softmax, read by G5)
  f16* Xp = (f16*)(w8);
  f16* Tp = (f16*)(w8 + 16 * MiB);
  f16* Yt = (f16*)(w8 + 32 * MiB);
  f16* Wp = (f16*)(w8 + 40 * MiB);
  f16* Rp = (f16*)(w8 + 42 * MiB);
  f16* Rtp = (f16*)(w8 + 46 * MiB);
  f16* Mtp = (f16*)(w8 + 50 * MiB);
  f16* Lh = (f16*)(w8 + 54 * MiB);
  f16* Pp = (f16*)(w8);

  const long sR = (long)D * D, sX = (long)Bq * D;
  const long sL = (long)Bq * Bq;
  const dim3 blk(256), blk512(512);

  // fused elementwise splits (X, R, W) + R-transpose split
  split_fused<<<dim3(6144), blk, 0, stream>>>(X, R, Wl, Xp, Rp, Wp, sX, sR);
  split_t2<<<dim3(D / 64, D / 64), blk, 0, stream>>>(R, Rtp, D, D, sR);

  // G1: Mt = Rt . R^T  (split2 out), grid 128
  gemm_mp<2, 64, 1, false, 2><<<dim3(D / 64, D / 128), blk, 0, stream>>>(
      Rtp, Rp, Mtp, nullptr, D, D, D, sR, sR, sR, 1.f);
  // G3: Yt = Wp . (Xp h-plane)^T = (X W^T)^T  (f16), dp, grid 256
  gemm_dp<1, 2, false><<<dim3(Bq / 128, D / 128), blk512, 0, stream>>>(
      Wp, Xp, Yt, nullptr, D, Bq, D, 0, 0, 0, 1.f);
  // G2: T = Xp . Mt^T  (split2 out), dp, grid 256
  gemm_dp<2, 1, false><<<dim3(D / 128, Bq / 128), blk512, 0, stream>>>(
      Xp, Mtp, Tp, nullptr, Bq, D, D, sX, sR, sX, 1.f);
  // G4: L = scale * Tp . Xp^T  (split2-f16 out), product-phase q4, grid 256
  gemm_q4<<<dim3(Bq / 256, Bq / 256), blk512, 0, stream>>>(
      Tp, Xp, Lh, sL, Bq, D, sX, sX, 0.03125f);
  // softmax rows (h+m combine) -> f16 P (overwrites Xp/Tp)
  softmax_ps<<<dim3(Bq), blk, 0, stream>>>(Lh, sL, Pp);
  // G5: out = Pp . Yt^T + bias  (fp32), dp, grid 256
  gemm_dp<1, 0, true><<<dim3(D / 128, Bq / 128), blk512, 0, stream>>>(
      Pp, Yt, out, bias, Bq, D, Bq, 0, 0, 0, 1.f);
}

// Round 9
// 235.476 us; speedup vs baseline: 1.7147x; 1.7147x over previous
//
#include <hip/hip_runtime.h>
#include <math.h>
#include <stdint.h>

using f16 = _Float16;
using half8 = __attribute__((ext_vector_type(8))) f16;
using half4 = __attribute__((ext_vector_type(4))) f16;
using f32x4 = __attribute__((ext_vector_type(4))) float;

__device__ __forceinline__ void gl_lds16(const f16* g, f16* l) {
  __builtin_amdgcn_global_load_lds(
      (const __attribute__((address_space(1))) void*)g,
      (__attribute__((address_space(3))) void*)l, 16, 0, 0);
}

// ---------------------------------------------------------------------------
// 256^2-tile Markidis GEMM (round-6 q2 body — best measured: 95.7us,
// MfmaUtil 49, FETCH 74MB). Barrier-free inner tile, full drain at tile top
// (the drain doubles as an inter-block k-synchronizer preserving L2 panel
// sharing — round-8's counted-vmcnt variant desynced blocks and tripled HBM
// fetch). Epilogue: split2-f16 planes.
// ---------------------------------------------------------------------------
__global__ __launch_bounds__(512, 2) void gemm_q2(
    const f16* __restrict__ Ap, const f16* __restrict__ Bp,
    f16* __restrict__ Ch, long sCp, int N, int K, long sAp, long sBp,
    float scale) {
  // buffer (granules of 16B): [A: pl*1024 + r*4 + kg | B: 2048 + same]
  __shared__ f16 lds[2 * 4096 * 8];
  const int tid = threadIdx.x;
  const int lane = tid & 63;
  const int wave = tid >> 6;
  const int wr = (wave >> 2) * 128;
  const int wc = (wave & 3) * 64;

  const int nwg = gridDim.x * gridDim.y;
  int bid = blockIdx.y * gridDim.x + blockIdx.x;
  bid = (bid & 7) * (nwg >> 3) + (bid >> 3);  // XCD-aware (nwg % 8 == 0)
  const int bm = (bid / gridDim.x) * 256;
  const int bn = (bid % gridDim.x) * 256;

  const int nt = K / 32;

  // stage part i (0..7) of tile t: 512 granules, 1 gl_lds/thread.
  auto stage = [&](int t, int i) {
    const int g0 = i * 512 + wave * 64;  // wave-uniform granule base
    const int ga = g0 + lane;
    const bool isB = ga >= 2048;
    const int gl = ga & 2047;
    const int pl = gl >> 10;
    const int gp = gl & 1023;
    const int r = gp >> 2;
    const int cg = (gp & 3) ^ ((r >> 1) & 3);  // XOR-swizzled source granule
    const f16* gs = (isB ? Bp + (size_t)pl * sBp + (size_t)(bn + r) * K
                         : Ap + (size_t)pl * sAp + (size_t)(bm + r) * K) +
                    t * 32 + cg * 8;
    gl_lds16(gs, &lds[((size_t)(t & 1) * 4096 + g0) * 8]);
  };

  // fragment ds_read offsets (halfs within buffer), swizzled
  int aoff[2][8], boff[2][4];
#pragma unroll
  for (int pl = 0; pl < 2; ++pl) {
#pragma unroll
    for (int fr = 0; fr < 8; ++fr) {
      const int row = wr + fr * 16 + (lane & 15);
      const int kg = (lane >> 4) ^ ((row >> 1) & 3);
      aoff[pl][fr] = (pl * 1024 + row * 4 + kg) * 8;
    }
#pragma unroll
    for (int fc = 0; fc < 4; ++fc) {
      const int col = wc + fc * 16 + (lane & 15);
      const int kg = (lane >> 4) ^ ((col >> 1) & 3);
      boff[pl][fc] = (2048 + pl * 1024 + col * 4 + kg) * 8;
    }
  }

  f32x4 acc[8][4];
#pragma unroll
  for (int m = 0; m < 8; ++m)
#pragma unroll
    for (int n = 0; n < 4; ++n) acc[m][n] = (f32x4){0.f, 0.f, 0.f, 0.f};

  half8 af0[2][4], af1[2][4], bf0[2][2], bf1[2][2];

#define LOAD_A(dst, h)                                          \
  _Pragma("unroll") for (int pl = 0; pl < 2; ++pl)              \
      _Pragma("unroll") for (int i = 0; i < 4; ++i) dst[pl][i] = \
          *(const half8*)&buf[aoff[pl][(h) * 4 + i]];
#define LOAD_B(dst, h)                                          \
  _Pragma("unroll") for (int pl = 0; pl < 2; ++pl)              \
      _Pragma("unroll") for (int j = 0; j < 2; ++j) dst[pl][j] = \
          *(const half8*)&buf[boff[pl][(h) * 2 + j]];
#define MFMA_Q(A, B, ah, bh)                                                  \
  _Pragma("unroll") for (int i = 0; i < 4; ++i)                               \
      _Pragma("unroll") for (int j = 0; j < 2; ++j) {                         \
    f32x4& c = acc[(ah) * 4 + i][(bh) * 2 + j];                               \
    c = __builtin_amdgcn_mfma_f32_16x16x32_f16(A[0][i], B[0][j], c, 0, 0, 0); \
    c = __builtin_amdgcn_mfma_f32_16x16x32_f16(A[0][i], B[1][j], c, 0, 0, 0); \
    c = __builtin_amdgcn_mfma_f32_16x16x32_f16(A[1][i], B[0][j], c, 0, 0, 0); \
  }
#define SBAR0() __builtin_amdgcn_sched_barrier(0)

  // prologue: prime tile 0
#pragma unroll
  for (int i = 0; i < 8; ++i) stage(0, i);

  for (int t = 0; t < nt; ++t) {
    const f16* buf = &lds[(size_t)(t & 1) * 4096 * 8];
    asm volatile("s_waitcnt vmcnt(0)" ::: "memory");
    asm volatile("s_barrier" ::: "memory");
    const bool pf = (t + 1 < nt);

    // issue Q1 frags + first half of next-tile staging
    LOAD_A(af0, 0);
    LOAD_B(bf0, 0);
    if (pf) { stage(t + 1, 0); stage(t + 1, 1); stage(t + 1, 2); stage(t + 1, 3); }
    SBAR0();
    LOAD_B(bf1, 1);  // prefetch Q2 frags
    SBAR0();
    __builtin_amdgcn_s_setprio(1);
    MFMA_Q(af0, bf0, 0, 0);
    __builtin_amdgcn_s_setprio(0);
    SBAR0();
    LOAD_A(af1, 1);  // prefetch Q3/Q4 A-frags
    if (pf) { stage(t + 1, 4); stage(t + 1, 5); stage(t + 1, 6); stage(t + 1, 7); }
    SBAR0();
    __builtin_amdgcn_s_setprio(1);
    MFMA_Q(af0, bf1, 0, 1);
    __builtin_amdgcn_s_setprio(0);
    SBAR0();
    LOAD_B(bf0, 0);  // re-read B0 for Q4 (keeps peak live frags low)
    SBAR0();
    __builtin_amdgcn_s_setprio(1);
    MFMA_Q(af1, bf1, 1, 1);
    __builtin_amdgcn_s_setprio(0);
    SBAR0();
    __builtin_amdgcn_s_setprio(1);
    MFMA_Q(af1, bf0, 1, 0);
    __builtin_amdgcn_s_setprio(0);
    SBAR0();
  }
#undef LOAD_A
#undef LOAD_B
#undef MFMA_Q
#undef SBAR0

  // epilogue: split2-f16 planes. C/D layout: col = lane&15, row = (lane>>4)*4+q
#pragma unroll
  for (int m = 0; m < 8; ++m) {
#pragma unroll
    for (int n = 0; n < 4; ++n) {
      const int col = bn + wc + n * 16 + (lane & 15);
#pragma unroll
      for (int q = 0; q < 4; ++q) {
        const int row = bm + wr + m * 16 + (lane >> 4) * 4 + q;
        const float v = acc[m][n][q] * scale;
        const f16 h = (f16)v;
        Ch[(size_t)row * N + col] = h;
        Ch[sCp + (size_t)row * N + col] = (f16)(v - (float)h);
      }
    }
  }
}

// ---------------------------------------------------------------------------
// 128^2 deep-pipelined GEMM (round 4), used for G2/G3/G5.
// ---------------------------------------------------------------------------
template <int NP, int EPI, bool BIASF>
__global__ __launch_bounds__(512, 2) void gemm_dp(
    const f16* __restrict__ Ap, const f16* __restrict__ Bp,
    void* __restrict__ Cv, const float* __restrict__ bias, int M, int N, int K,
    long sAp, long sBp, long sCp, float scale) {
  __shared__ f16 lds[3 * 2048 * 8];
  const int tid = threadIdx.x;
  const int lane = tid & 63;
  const int wave = tid >> 6;
  const int wr = (wave >> 1) * 32;
  const int wc = (wave & 1) * 64;

  const int nwg = gridDim.x * gridDim.y;
  int bid = blockIdx.y * gridDim.x + blockIdx.x;
  bid = (bid & 7) * (nwg >> 3) + (bid >> 3);
  const int bm = (bid / gridDim.x) * 128;
  const int bn = (bid % gridDim.x) * 128;

  constexpr int KSTEP = (NP == 2) ? 32 : 64;
  const int nt = K / KSTEP;

  auto stage = [&](int t, int i) {
    const int g0 = i * 512 + wave * 64;
    const int ga = g0 + lane;
    const bool isB = ga >= 1024;
    const int gl = ga & 1023;
    const int pl = gl >> 9;
    const int gp = gl & 511;
    const int r = gp >> 2;
    const int cg = (gp & 3) ^ ((r >> 1) & 3);
    const long sP = (NP == 2) ? (isB ? sBp : sAp) : 0;
    const int kOff = (NP == 2) ? 0 : pl * 32;
    const f16* gs = (isB ? Bp : Ap) + (size_t)pl * sP +
                    (size_t)((isB ? bn : bm) + r) * K + t * KSTEP + kOff +
                    cg * 8;
    gl_lds16(gs, &lds[((size_t)(t % 3) * 2048 + g0) * 8]);
  };

  int aoff[2][2], boff[2][4];
#pragma unroll
  for (int pl = 0; pl < 2; ++pl) {
#pragma unroll
    for (int m = 0; m < 2; ++m) {
      const int row = wr + m * 16 + (lane & 15);
      const int kg = (lane >> 4) ^ ((row >> 1) & 3);
      aoff[pl][m] = (pl * 512 + row * 4 + kg) * 8;
    }
#pragma unroll
    for (int n = 0; n < 4; ++n) {
      const int col = wc + n * 16 + (lane & 15);
      const int kg = (lane >> 4) ^ ((col >> 1) & 3);
      boff[pl][n] = (1024 + pl * 512 + col * 4 + kg) * 8;
    }
  }

  f32x4 acc[2][4];
#pragma unroll
  for (int m = 0; m < 2; ++m)
#pragma unroll
    for (int n = 0; n < 4; ++n) acc[m][n] = (f32x4){0.f, 0.f, 0.f, 0.f};

#pragma unroll
  for (int i = 0; i < 4; ++i) stage(0, i);
#pragma unroll
  for (int i = 0; i < 4; ++i) stage(1, i);

  for (int t = 0; t < nt; ++t) {
    const f16* buf = &lds[(size_t)(t % 3) * 2048 * 8];
    if (t + 1 < nt)
      asm volatile("s_waitcnt vmcnt(4)" ::: "memory");
    else
      asm volatile("s_waitcnt vmcnt(0)" ::: "memory");
    asm volatile("s_barrier" ::: "memory");

    half8 af[2][2], b0[2][2];
#pragma unroll
    for (int pl = 0; pl < 2; ++pl) {
#pragma unroll
      for (int m = 0; m < 2; ++m) af[pl][m] = *(const half8*)&buf[aoff[pl][m]];
#pragma unroll
      for (int j = 0; j < 2; ++j) b0[pl][j] = *(const half8*)&buf[boff[pl][j]];
    }
    if (t + 2 < nt) {
      stage(t + 2, 0);
      stage(t + 2, 1);
    }
    __builtin_amdgcn_sched_barrier(0);
    asm volatile("s_barrier" ::: "memory");
    asm volatile("s_waitcnt lgkmcnt(0)" ::: "memory");
    __builtin_amdgcn_sched_barrier(0);
    __builtin_amdgcn_s_setprio(1);
#pragma unroll
    for (int m = 0; m < 2; ++m) {
#pragma unroll
      for (int j = 0; j < 2; ++j) {
        acc[m][j] = __builtin_amdgcn_mfma_f32_16x16x32_f16(af[0][m], b0[0][j],
                                                           acc[m][j], 0, 0, 0);
        if (NP == 2) {
          acc[m][j] = __builtin_amdgcn_mfma_f32_16x16x32_f16(
              af[0][m], b0[1][j], acc[m][j], 0, 0, 0);
          acc[m][j] = __builtin_amdgcn_mfma_f32_16x16x32_f16(
              af[1][m], b0[0][j], acc[m][j], 0, 0, 0);
        } else {
          acc[m][j] = __builtin_amdgcn_mfma_f32_16x16x32_f16(
              af[1][m], b0[1][j], acc[m][j], 0, 0, 0);
        }
      }
    }
    __builtin_amdgcn_s_setprio(0);
    __builtin_amdgcn_sched_barrier(0);
    asm volatile("s_barrier" ::: "memory");

    half8 b1[2][2];
#pragma unroll
    for (int pl = 0; pl < 2; ++pl)
#pragma unroll
      for (int j = 0; j < 2; ++j)
        b1[pl][j] = *(const half8*)&buf[boff[pl][2 + j]];
    if (t + 2 < nt) {
      stage(t + 2, 2);
      stage(t + 2, 3);
    }
    __builtin_amdgcn_sched_barrier(0);
    asm volatile("s_barrier" ::: "memory");
    asm volatile("s_waitcnt lgkmcnt(0)" ::: "memory");
    __builtin_amdgcn_sched_barrier(0);
    __builtin_amdgcn_s_setprio(1);
#pragma unroll
    for (int m = 0; m < 2; ++m) {
#pragma unroll
      for (int j = 0; j < 2; ++j) {
        acc[m][2 + j] = __builtin_amdgcn_mfma_f32_16x16x32_f16(
            af[0][m], b1[0][j], acc[m][2 + j], 0, 0, 0);
        if (NP == 2) {
          acc[m][2 + j] = __builtin_amdgcn_mfma_f32_16x16x32_f16(
              af[0][m], b1[1][j], acc[m][2 + j], 0, 0, 0);
          acc[m][2 + j] = __builtin_amdgcn_mfma_f32_16x16x32_f16(
              af[1][m], b1[0][j], acc[m][2 + j], 0, 0, 0);
        } else {
          acc[m][2 + j] = __builtin_amdgcn_mfma_f32_16x16x32_f16(
              af[1][m], b1[1][j], acc[m][2 + j], 0, 0, 0);
        }
      }
    }
    __builtin_amdgcn_s_setprio(0);
    __builtin_amdgcn_sched_barrier(0);
  }

#pragma unroll
  for (int m = 0; m < 2; ++m) {
#pragma unroll
    for (int n = 0; n < 4; ++n) {
      const int col = bn + wc + n * 16 + (lane & 15);
      const float bv = BIASF ? bias[col] : 0.f;
#pragma unroll
      for (int q = 0; q < 4; ++q) {
        const int row = bm + wr + m * 16 + (lane >> 4) * 4 + q;
        float v = acc[m][n][q] * scale;
        if (EPI == 0) {
          ((float*)Cv)[(size_t)row * N + col] = v + bv;
        } else if (EPI == 1) {
          f16* C = (f16*)Cv;
          const f16 h = (f16)v;
          C[(size_t)row * N + col] = h;
          C[sCp + (size_t)row * N + col] = (f16)(v - (float)h);
        } else {
          ((f16*)Cv)[(size_t)row * N + col] = (f16)v;
        }
      }
    }
  }
}

// ---------------------------------------------------------------------------
// Round-3 2-barrier kernel, kept for the tiny G1 (grid 128)
// ---------------------------------------------------------------------------
template <int NP, int TN, int EPI, bool BIASF, int MINW>
__global__ __launch_bounds__(256, MINW) void gemm_mp(
    const f16* __restrict__ Ap, const f16* __restrict__ Bp,
    void* __restrict__ Cv, const float* __restrict__ bias, int M, int N, int K,
    long sAp, long sBp, long sCp, float scale) {
  constexpr int FR = (TN == 128) ? 4 : 2;
  constexpr int FC = 4;
  constexpr int AG = NP * 512;
  constexpr int BPG = TN * 4;
  __shared__ f16 As[NP * 128 * 32];
  __shared__ f16 Bs[NP * TN * 32];
  const int tid = threadIdx.x;
  const int lane = tid & 63;
  const int wave = tid >> 6;
  const int wr = (TN == 128) ? (wave >> 1) * 64 : wave * 32;
  const int wc = (TN == 128) ? (wave & 1) * 64 : 0;

  const int nwg = gridDim.x * gridDim.y;
  int bid = blockIdx.y * gridDim.x + blockIdx.x;
  bid = (bid & 7) * (nwg >> 3) + (bid >> 3);
  const int bm = (bid / gridDim.x) * 128;
  const int bn = (bid % gridDim.x) * TN;

  int aoff[NP][FR], boff[NP][FC];
#pragma unroll
  for (int p = 0; p < NP; ++p) {
#pragma unroll
    for (int m = 0; m < FR; ++m) {
      const int row = wr + m * 16 + (lane & 15);
      const int kga = (lane >> 4) ^ ((row >> 1) & 3);
      aoff[p][m] = (p * 512 + row * 4 + kga) * 8;
    }
#pragma unroll
    for (int n = 0; n < FC; ++n) {
      const int col = wc + n * 16 + (lane & 15);
      const int kgb = (lane >> 4) ^ ((col >> 1) & 3);
      boff[p][n] = (p * BPG + col * 4 + kgb) * 8;
    }
  }

  f32x4 acc[FR][FC];
#pragma unroll
  for (int m = 0; m < FR; ++m)
#pragma unroll
    for (int n = 0; n < FC; ++n) acc[m][n] = (f32x4){0.f, 0.f, 0.f, 0.f};

  for (int k0 = 0; k0 < K; k0 += 32) {
#pragma unroll
    for (int i = 0; i < (NP * (512 + TN * 4)) / 256; ++i) {
      const int g0 = i * 256 + wave * 64;
      const bool isB = g0 >= AG;
      const int ga0 = g0 - (isB ? AG : 0);
      const int ga = ga0 + lane;
      const int pl = isB ? (ga / BPG) : (ga >> 9);
      const int gp = isB ? (ga % BPG) : (ga & 511);
      const int r = gp >> 2;
      const int cg = (gp & 3) ^ ((r >> 1) & 3);
      const f16* gs = (isB ? Bp + (size_t)pl * sBp + (size_t)(bn + r) * K
                           : Ap + (size_t)pl * sAp + (size_t)(bm + r) * K) +
                      k0 + cg * 8;
      f16* ld = (isB ? Bs : As) + (size_t)ga0 * 8;
      gl_lds16(gs, ld);
    }
    __syncthreads();

    half8 af[NP][FR], bf[NP][FC];
#pragma unroll
    for (int p = 0; p < NP; ++p) {
#pragma unroll
      for (int m = 0; m < FR; ++m) af[p][m] = *(const half8*)&As[aoff[p][m]];
#pragma unroll
      for (int n = 0; n < FC; ++n) bf[p][n] = *(const half8*)&Bs[boff[p][n]];
    }
#pragma unroll
    for (int m = 0; m < FR; ++m) {
#pragma unroll
      for (int n = 0; n < FC; ++n) {
        acc[m][n] = __builtin_amdgcn_mfma_f32_16x16x32_f16(af[0][m], bf[0][n],
                                                           acc[m][n], 0, 0, 0);
        if (NP == 2) {
          acc[m][n] = __builtin_amdgcn_mfma_f32_16x16x32_f16(
              af[0][m], bf[1][n], acc[m][n], 0, 0, 0);
          acc[m][n] = __builtin_amdgcn_mfma_f32_16x16x32_f16(
              af[1][m], bf[0][n], acc[m][n], 0, 0, 0);
        }
      }
    }
    __syncthreads();
  }

#pragma unroll
  for (int m = 0; m < FR; ++m) {
#pragma unroll
    for (int n = 0; n < FC; ++n) {
      const int col = bn + wc + n * 16 + (lane & 15);
      const float bv = BIASF ? bias[col] : 0.f;
#pragma unroll
      for (int q = 0; q < 4; ++q) {
        const int row = bm + wr + m * 16 + (lane >> 4) * 4 + q;
        float v = acc[m][n][q] * scale;
        if (EPI == 0) {
          ((float*)Cv)[(size_t)row * N + col] = v + bv;
        } else if (EPI == 1) {
          f16* C = (f16*)Cv;
          const f16 h = (f16)v;
          C[(size_t)row * N + col] = h;
          C[sCp + (size_t)row * N + col] = (f16)(v - (float)h);
        } else {
          ((f16*)Cv)[(size_t)row * N + col] = (f16)v;
        }
      }
    }
  }
}

// fused elementwise splits: X->split2, R->split2, W->split1 (one launch)
__global__ __launch_bounds__(256) void split_fused(
    const float* __restrict__ X, const float* __restrict__ R,
    const float* __restrict__ W, f16* __restrict__ Xp, f16* __restrict__ Rp,
    f16* __restrict__ Wp, long sX, long sR) {
  const int b = blockIdx.x;
  const float* in;
  f16* out;
  long ps;
  int np, i;
  if (b < 4096) {
    in = X; out = Xp; ps = sX; np = 2; i = b * 256 + threadIdx.x;
  } else if (b < 5120) {
    in = R; out = Rp; ps = sR; np = 2; i = (b - 4096) * 256 + threadIdx.x;
  } else {
    in = W; out = Wp; ps = 0; np = 1; i = (b - 5120) * 256 + threadIdx.x;
  }
  const float4 v = ((const float4*)in)[i];
  const float vv[4] = {v.x, v.y, v.z, v.w};
  half4 h, mm;
#pragma unroll
  for (int q = 0; q < 4; ++q) {
    h[q] = (f16)vv[q];
    mm[q] = (f16)(vv[q] - (float)h[q]);
  }
  ((half4*)out)[i] = h;
  if (np == 2) ((half4*)(out + ps))[i] = mm;
}

// fp32 [Mr,Nc] -> 2 fp16 planes of the TRANSPOSE [Nc,Mr]
__global__ __launch_bounds__(256) void split_t2(const float* __restrict__ in,
                                                f16* __restrict__ out, int Mr,
                                                int Nc, long planeStride) {
  __shared__ float Ls[64][65];
  const int i0 = blockIdx.y * 64;
  const int j0 = blockIdx.x * 64;
  const int t = threadIdx.x;
  const int r = t >> 4;
  const int c = (t & 15) * 4;
#pragma unroll
  for (int i = 0; i < 4; ++i) {
    const float4 v =
        *(const float4*)&in[(size_t)(i0 + r + i * 16) * Nc + j0 + c];
    Ls[r + i * 16][c + 0] = v.x;
    Ls[r + i * 16][c + 1] = v.y;
    Ls[r + i * 16][c + 2] = v.z;
    Ls[r + i * 16][c + 3] = v.w;
  }
  __syncthreads();
#pragma unroll
  for (int i = 0; i < 4; ++i) {
    const int r2 = r + i * 16;
    half4 h, mm;
#pragma unroll
    for (int q = 0; q < 4; ++q) {
      const float v = Ls[c + q][r2];
      h[q] = (f16)v;
      mm[q] = (f16)(v - (float)h[q]);
    }
    *(half4*)&out[(size_t)(j0 + r2) * Mr + i0 + c] = h;
    *(half4*)&out[planeStride + (size_t)(j0 + r2) * Mr + i0 + c] = mm;
  }
}

// row softmax over split2-f16 logits [4096] -> f16 P row; one block per row.
__global__ __launch_bounds__(256) void softmax_ps(const f16* __restrict__ Lh,
                                                  long sL,
                                                  f16* __restrict__ P) {
  __shared__ float row[4096];
  __shared__ float red[8];
  const int rix = blockIdx.x;
  const f16* ph = Lh + (size_t)rix * 4096;
  const f16* pm = ph + sL;
  f16* o = P + (size_t)rix * 4096;
  const int tid = threadIdx.x;

  float mx = -INFINITY;
  for (int i = tid * 8; i < 4096; i += 2048) {
    const half8 h = *(const half8*)&ph[i];
    const half8 mseg = *(const half8*)&pm[i];
#pragma unroll
    for (int q = 0; q < 8; ++q) {
      const float v = (float)h[q] + (float)mseg[q];
      row[i + q] = v;
      mx = fmaxf(mx, v);
    }
  }
#pragma unroll
  for (int off = 32; off > 0; off >>= 1) mx = fmaxf(mx, __shfl_xor(mx, off));
  if ((tid & 63) == 0) red[tid >> 6] = mx;
  __syncthreads();
  mx = fmaxf(fmaxf(red[0], red[1]), fmaxf(red[2], red[3]));

  float s = 0.f;
  for (int i = tid * 4; i < 4096; i += 1024) {
    float4 v = *reinterpret_cast<const float4*>(&row[i]);
    v.x = expf(v.x - mx);
    v.y = expf(v.y - mx);
    v.z = expf(v.z - mx);
    v.w = expf(v.w - mx);
    s += v.x + v.y + v.z + v.w;
    *reinterpret_cast<float4*>(&row[i]) = v;
  }
#pragma unroll
  for (int off = 32; off > 0; off >>= 1) s += __shfl_xor(s, off);
  if ((tid & 63) == 0) red[4 + (tid >> 6)] = s;
  __syncthreads();
  s = red[4] + red[5] + red[6] + red[7];
  const float inv = 1.0f / s;

  for (int i = tid * 8; i < 4096; i += 2048) {
    half8 h;
#pragma unroll
    for (int q = 0; q < 8; ++q) h[q] = (f16)(row[i + q] * inv);
    *(half8*)&o[i] = h;
  }
}

extern "C" void kernel_launch(void* const* d_in, const int* in_sizes, int n_in,
                              void* d_out, int out_size, void* d_ws,
                              size_t ws_size, hipStream_t stream) {
  const float* X = (const float*)d_in[0];   // [4096,1024]
  const float* R = (const float*)d_in[1];   // [1024,1024]
  const float* Wl = (const float*)d_in[2];  // [1024,1024] (out,in)
  const float* bias = (const float*)d_in[3];
  float* out = (float*)d_out;

  const int Bq = 4096, D = 1024;
  const size_t MiB = 1 << 20;
  uint8_t* w8 = (uint8_t*)d_ws;
  // Layout (live-range checked):
  //  Xp [0,16) split2 X           (dead after G4; Pp overwrites)
  //  Tp [16,32) split2 T          (dead after G4)
  //  Yt [32,40) f16 (X W^T)^T     (live until G5)
  //  Wp [40,42) f16 W             (dead after G3)
  //  Rp [42,46) Rtp [46,50) Mtp [50,54)  (dead after G2)
  //  Lh [54,70) Lm [70,86) split2 logits (dead after softmax)
  //  Pp [0,32)  f16 P             (written by softmax, read by G5)
  f16* Xp = (f16*)(w8);
  f16* Tp = (f16*)(w8 + 16 * MiB);
  f16* Yt = (f16*)(w8 + 32 * MiB);
  f16* Wp = (f16*)(w8 + 40 * MiB);
  f16* Rp = (f16*)(w8 + 42 * MiB);
  f16* Rtp = (f16*)(w8 + 46 * MiB);
  f16* Mtp = (f16*)(w8 + 50 * MiB);
  f16* Lh = (f16*)(w8 + 54 * MiB);
  f16* Pp = (f16*)(w8);

  const long sR = (long)D * D, sX = (long)Bq * D;
  const long sL = (long)Bq * Bq;
  const dim3 blk(256), blk512(512);

  // fused elementwise splits (X, R, W) + R-transpose split
  split_fused<<<dim3(6144), blk, 0, stream>>>(X, R, Wl, Xp, Rp, Wp, sX, sR);
  split_t2<<<dim3(D / 64, D / 64), blk, 0, stream>>>(R, Rtp, D, D, sR);

  // G1: Mt = Rt . R^T  (split2 out), grid 128
  gemm_mp<2, 64, 1, false, 2><<<dim3(D / 64, D / 128), blk, 0, stream>>>(
      Rtp, Rp, Mtp, nullptr, D, D, D, sR, sR, sR, 1.f);
  // G3: Yt = Wp . (Xp h-plane)^T = (X W^T)^T  (f16), dp, grid 256
  gemm_dp<1, 2, false><<<dim3(Bq / 128, D / 128), blk512, 0, stream>>>(
      Wp, Xp, Yt, nullptr, D, Bq, D, 0, 0, 0, 1.f);
  // G2: T = Xp . Mt^T  (split2 out), dp, grid 256
  gemm_dp<2, 1, false><<<dim3(D / 128, Bq / 128), blk512, 0, stream>>>(
      Xp, Mtp, Tp, nullptr, Bq, D, D, sX, sR, sX, 1.f);
  // G4: L = scale * Tp . Xp^T  (split2-f16 out), round-6 q2 body, grid 256
  gemm_q2<<<dim3(Bq / 256, Bq / 256), blk512, 0, stream>>>(
      Tp, Xp, Lh, sL, Bq, D, sX, sX, 0.03125f);
  // softmax rows (h+m combine) -> f16 P (overwrites Xp/Tp)
  softmax_ps<<<dim3(Bq), blk, 0, stream>>>(Lh, sL, Pp);
  // G5: out = Pp . Yt^T + bias  (fp32), dp, grid 256
  gemm_dp<1, 0, true><<<dim3(D / 128, Bq / 128), blk512, 0, stream>>>(
      Pp, Yt, out, bias, Bq, D, Bq, 0, 0, 0, 1.f);
}

// Round 10
// 228.501 us; speedup vs baseline: 1.7670x; 1.0305x over previous
//
#include <hip/hip_runtime.h>
#include <math.h>
#include <stdint.h>

using f16 = _Float16;
using half8 = __attribute__((ext_vector_type(8))) f16;
using half4 = __attribute__((ext_vector_type(4))) f16;
using f32x4 = __attribute__((ext_vector_type(4))) float;

__device__ __forceinline__ void gl_lds16(const f16* g, f16* l) {
  __builtin_amdgcn_global_load_lds(
      (const __attribute__((address_space(1))) void*)g,
      (__attribute__((address_space(3))) void*)l, 16, 0, 0);
}

// ---------------------------------------------------------------------------
// 256^2-tile Markidis GEMM (round-6 q2 body, best measured). Barrier-free
// inner tile, full drain at tile top (drain doubles as inter-block k-sync
// preserving L2 panel sharing — round-8 counted-vmcnt desynced blocks and
// tripled HBM fetch). Round-10 tweak: all 8 next-tile stages issued at tile
// top (max slack before next drain). Epilogue: split2-f16 planes.
// ---------------------------------------------------------------------------
__global__ __launch_bounds__(512, 2) void gemm_q2(
    const f16* __restrict__ Ap, const f16* __restrict__ Bp,
    f16* __restrict__ Ch, long sCp, int N, int K, long sAp, long sBp,
    float scale) {
  __shared__ f16 lds[2 * 4096 * 8];
  const int tid = threadIdx.x;
  const int lane = tid & 63;
  const int wave = tid >> 6;
  const int wr = (wave >> 2) * 128;
  const int wc = (wave & 3) * 64;

  const int nwg = gridDim.x * gridDim.y;
  int bid = blockIdx.y * gridDim.x + blockIdx.x;
  bid = (bid & 7) * (nwg >> 3) + (bid >> 3);  // XCD-aware (nwg % 8 == 0)
  const int bm = (bid / gridDim.x) * 256;
  const int bn = (bid % gridDim.x) * 256;

  const int nt = K / 32;

  auto stage = [&](int t, int i) {
    const int g0 = i * 512 + wave * 64;  // wave-uniform granule base
    const int ga = g0 + lane;
    const bool isB = ga >= 2048;
    const int gl = ga & 2047;
    const int pl = gl >> 10;
    const int gp = gl & 1023;
    const int r = gp >> 2;
    const int cg = (gp & 3) ^ ((r >> 1) & 3);  // XOR-swizzled source granule
    const f16* gs = (isB ? Bp + (size_t)pl * sBp + (size_t)(bn + r) * K
                         : Ap + (size_t)pl * sAp + (size_t)(bm + r) * K) +
                    t * 32 + cg * 8;
    gl_lds16(gs, &lds[((size_t)(t & 1) * 4096 + g0) * 8]);
  };

  int aoff[2][8], boff[2][4];
#pragma unroll
  for (int pl = 0; pl < 2; ++pl) {
#pragma unroll
    for (int fr = 0; fr < 8; ++fr) {
      const int row = wr + fr * 16 + (lane & 15);
      const int kg = (lane >> 4) ^ ((row >> 1) & 3);
      aoff[pl][fr] = (pl * 1024 + row * 4 + kg) * 8;
    }
#pragma unroll
    for (int fc = 0; fc < 4; ++fc) {
      const int col = wc + fc * 16 + (lane & 15);
      const int kg = (lane >> 4) ^ ((col >> 1) & 3);
      boff[pl][fc] = (2048 + pl * 1024 + col * 4 + kg) * 8;
    }
  }

  f32x4 acc[8][4];
#pragma unroll
  for (int m = 0; m < 8; ++m)
#pragma unroll
    for (int n = 0; n < 4; ++n) acc[m][n] = (f32x4){0.f, 0.f, 0.f, 0.f};

  half8 af0[2][4], af1[2][4], bf0[2][2], bf1[2][2];

#define LOAD_A(dst, h)                                          \
  _Pragma("unroll") for (int pl = 0; pl < 2; ++pl)              \
      _Pragma("unroll") for (int i = 0; i < 4; ++i) dst[pl][i] = \
          *(const half8*)&buf[aoff[pl][(h) * 4 + i]];
#define LOAD_B(dst, h)                                          \
  _Pragma("unroll") for (int pl = 0; pl < 2; ++pl)              \
      _Pragma("unroll") for (int j = 0; j < 2; ++j) dst[pl][j] = \
          *(const half8*)&buf[boff[pl][(h) * 2 + j]];
#define MFMA_Q(A, B, ah, bh)                                                  \
  _Pragma("unroll") for (int i = 0; i < 4; ++i)                               \
      _Pragma("unroll") for (int j = 0; j < 2; ++j) {                         \
    f32x4& c = acc[(ah) * 4 + i][(bh) * 2 + j];                               \
    c = __builtin_amdgcn_mfma_f32_16x16x32_f16(A[0][i], B[0][j], c, 0, 0, 0); \
    c = __builtin_amdgcn_mfma_f32_16x16x32_f16(A[0][i], B[1][j], c, 0, 0, 0); \
    c = __builtin_amdgcn_mfma_f32_16x16x32_f16(A[1][i], B[0][j], c, 0, 0, 0); \
  }
#define SBAR0() __builtin_amdgcn_sched_barrier(0)

  // prologue: prime tile 0
#pragma unroll
  for (int i = 0; i < 8; ++i) stage(0, i);

  for (int t = 0; t < nt; ++t) {
    const f16* buf = &lds[(size_t)(t & 1) * 4096 * 8];
    asm volatile("s_waitcnt vmcnt(0)" ::: "memory");
    asm volatile("s_barrier" ::: "memory");
    const bool pf = (t + 1 < nt);

    // issue Q1 frags + ALL next-tile staging (max slack before next drain)
    LOAD_A(af0, 0);
    LOAD_B(bf0, 0);
    if (pf) {
      stage(t + 1, 0); stage(t + 1, 1); stage(t + 1, 2); stage(t + 1, 3);
      stage(t + 1, 4); stage(t + 1, 5); stage(t + 1, 6); stage(t + 1, 7);
    }
    SBAR0();
    LOAD_B(bf1, 1);  // prefetch Q2 frags
    SBAR0();
    __builtin_amdgcn_s_setprio(1);
    MFMA_Q(af0, bf0, 0, 0);
    __builtin_amdgcn_s_setprio(0);
    SBAR0();
    LOAD_A(af1, 1);  // prefetch Q3/Q4 A-frags
    SBAR0();
    __builtin_amdgcn_s_setprio(1);
    MFMA_Q(af0, bf1, 0, 1);
    __builtin_amdgcn_s_setprio(0);
    SBAR0();
    LOAD_B(bf0, 0);  // re-read B0 for Q4 (keeps peak live frags low)
    SBAR0();
    __builtin_amdgcn_s_setprio(1);
    MFMA_Q(af1, bf1, 1, 1);
    __builtin_amdgcn_s_setprio(0);
    SBAR0();
    __builtin_amdgcn_s_setprio(1);
    MFMA_Q(af1, bf0, 1, 0);
    __builtin_amdgcn_s_setprio(0);
    SBAR0();
  }
#undef LOAD_A
#undef LOAD_B
#undef MFMA_Q
#undef SBAR0

  // epilogue: split2-f16 planes. C/D layout: col = lane&15, row = (lane>>4)*4+q
#pragma unroll
  for (int m = 0; m < 8; ++m) {
#pragma unroll
    for (int n = 0; n < 4; ++n) {
      const int col = bn + wc + n * 16 + (lane & 15);
#pragma unroll
      for (int q = 0; q < 4; ++q) {
        const int row = bm + wr + m * 16 + (lane >> 4) * 4 + q;
        const float v = acc[m][n][q] * scale;
        const f16 h = (f16)v;
        Ch[(size_t)row * N + col] = h;
        Ch[sCp + (size_t)row * N + col] = (f16)(v - (float)h);
      }
    }
  }
}

// ---------------------------------------------------------------------------
// 128^2 deep-pipelined GEMM, barrier-free inner tile (round 10): one barrier
// + one counted vmcnt per K-tile; all 12 frag reads issued together; compiler
// counted-lgkm interleaves reads with MFMAs. Buffer rotation mod 3 means
// reads(buf t) and writes(buf t+2) never collide; each wave's lgkm waits
// complete its reads before it can pass the next tile-top barrier, so the
// write of buf[(t+3)%3==t%3] issued after that barrier is safe.
// ---------------------------------------------------------------------------
template <int NP, int EPI, bool BIASF>
__global__ __launch_bounds__(512, 2) void gemm_dp(
    const f16* __restrict__ Ap, const f16* __restrict__ Bp,
    void* __restrict__ Cv, const float* __restrict__ bias, int M, int N, int K,
    long sAp, long sBp, long sCp, float scale) {
  __shared__ f16 lds[3 * 2048 * 8];
  const int tid = threadIdx.x;
  const int lane = tid & 63;
  const int wave = tid >> 6;
  const int wr = (wave >> 1) * 32;
  const int wc = (wave & 1) * 64;

  const int nwg = gridDim.x * gridDim.y;
  int bid = blockIdx.y * gridDim.x + blockIdx.x;
  bid = (bid & 7) * (nwg >> 3) + (bid >> 3);
  const int bm = (bid / gridDim.x) * 128;
  const int bn = (bid % gridDim.x) * 128;

  constexpr int KSTEP = (NP == 2) ? 32 : 64;
  const int nt = K / KSTEP;

  auto stage = [&](int t, int i) {
    const int g0 = i * 512 + wave * 64;
    const int ga = g0 + lane;
    const bool isB = ga >= 1024;
    const int gl = ga & 1023;
    const int pl = gl >> 9;
    const int gp = gl & 511;
    const int r = gp >> 2;
    const int cg = (gp & 3) ^ ((r >> 1) & 3);
    const long sP = (NP == 2) ? (isB ? sBp : sAp) : 0;
    const int kOff = (NP == 2) ? 0 : pl * 32;
    const f16* gs = (isB ? Bp : Ap) + (size_t)pl * sP +
                    (size_t)((isB ? bn : bm) + r) * K + t * KSTEP + kOff +
                    cg * 8;
    gl_lds16(gs, &lds[((size_t)(t % 3) * 2048 + g0) * 8]);
  };

  int aoff[2][2], boff[2][4];
#pragma unroll
  for (int pl = 0; pl < 2; ++pl) {
#pragma unroll
    for (int m = 0; m < 2; ++m) {
      const int row = wr + m * 16 + (lane & 15);
      const int kg = (lane >> 4) ^ ((row >> 1) & 3);
      aoff[pl][m] = (pl * 512 + row * 4 + kg) * 8;
    }
#pragma unroll
    for (int n = 0; n < 4; ++n) {
      const int col = wc + n * 16 + (lane & 15);
      const int kg = (lane >> 4) ^ ((col >> 1) & 3);
      boff[pl][n] = (1024 + pl * 512 + col * 4 + kg) * 8;
    }
  }

  f32x4 acc[2][4];
#pragma unroll
  for (int m = 0; m < 2; ++m)
#pragma unroll
    for (int n = 0; n < 4; ++n) acc[m][n] = (f32x4){0.f, 0.f, 0.f, 0.f};

#pragma unroll
  for (int i = 0; i < 4; ++i) stage(0, i);
#pragma unroll
  for (int i = 0; i < 4; ++i) stage(1, i);

  for (int t = 0; t < nt; ++t) {
    const f16* buf = &lds[(size_t)(t % 3) * 2048 * 8];
    if (t + 1 < nt)
      asm volatile("s_waitcnt vmcnt(4)" ::: "memory");
    else
      asm volatile("s_waitcnt vmcnt(0)" ::: "memory");
    asm volatile("s_barrier" ::: "memory");

    half8 af[2][2], bf[2][4];
#pragma unroll
    for (int pl = 0; pl < 2; ++pl) {
#pragma unroll
      for (int m = 0; m < 2; ++m) af[pl][m] = *(const half8*)&buf[aoff[pl][m]];
#pragma unroll
      for (int n = 0; n < 4; ++n) bf[pl][n] = *(const half8*)&buf[boff[pl][n]];
    }
    if (t + 2 < nt) {
      stage(t + 2, 0);
      stage(t + 2, 1);
      stage(t + 2, 2);
      stage(t + 2, 3);
    }
    __builtin_amdgcn_sched_barrier(0);
    __builtin_amdgcn_s_setprio(1);
#pragma unroll
    for (int m = 0; m < 2; ++m) {
#pragma unroll
      for (int n = 0; n < 4; ++n) {
        acc[m][n] = __builtin_amdgcn_mfma_f32_16x16x32_f16(af[0][m], bf[0][n],
                                                           acc[m][n], 0, 0, 0);
        if (NP == 2) {
          acc[m][n] = __builtin_amdgcn_mfma_f32_16x16x32_f16(
              af[0][m], bf[1][n], acc[m][n], 0, 0, 0);
          acc[m][n] = __builtin_amdgcn_mfma_f32_16x16x32_f16(
              af[1][m], bf[0][n], acc[m][n], 0, 0, 0);
        } else {
          acc[m][n] = __builtin_amdgcn_mfma_f32_16x16x32_f16(
              af[1][m], bf[1][n], acc[m][n], 0, 0, 0);
        }
      }
    }
    __builtin_amdgcn_s_setprio(0);
    __builtin_amdgcn_sched_barrier(0);
  }

#pragma unroll
  for (int m = 0; m < 2; ++m) {
#pragma unroll
    for (int n = 0; n < 4; ++n) {
      const int col = bn + wc + n * 16 + (lane & 15);
      const float bv = BIASF ? bias[col] : 0.f;
#pragma unroll
      for (int q = 0; q < 4; ++q) {
        const int row = bm + wr + m * 16 + (lane >> 4) * 4 + q;
        float v = acc[m][n][q] * scale;
        if (EPI == 0) {
          ((float*)Cv)[(size_t)row * N + col] = v + bv;
        } else if (EPI == 1) {
          f16* C = (f16*)Cv;
          const f16 h = (f16)v;
          C[(size_t)row * N + col] = h;
          C[sCp + (size_t)row * N + col] = (f16)(v - (float)h);
        } else {
          ((f16*)Cv)[(size_t)row * N + col] = (f16)v;
        }
      }
    }
  }
}

// ---------------------------------------------------------------------------
// Round-3 2-barrier kernel, kept for the tiny G1 (grid 128)
// ---------------------------------------------------------------------------
template <int NP, int TN, int EPI, bool BIASF, int MINW>
__global__ __launch_bounds__(256, MINW) void gemm_mp(
    const f16* __restrict__ Ap, const f16* __restrict__ Bp,
    void* __restrict__ Cv, const float* __restrict__ bias, int M, int N, int K,
    long sAp, long sBp, long sCp, float scale) {
  constexpr int FR = (TN == 128) ? 4 : 2;
  constexpr int FC = 4;
  constexpr int AG = NP * 512;
  constexpr int BPG = TN * 4;
  __shared__ f16 As[NP * 128 * 32];
  __shared__ f16 Bs[NP * TN * 32];
  const int tid = threadIdx.x;
  const int lane = tid & 63;
  const int wave = tid >> 6;
  const int wr = (TN == 128) ? (wave >> 1) * 64 : wave * 32;
  const int wc = (TN == 128) ? (wave & 1) * 64 : 0;

  const int nwg = gridDim.x * gridDim.y;
  int bid = blockIdx.y * gridDim.x + blockIdx.x;
  bid = (bid & 7) * (nwg >> 3) + (bid >> 3);
  const int bm = (bid / gridDim.x) * 128;
  const int bn = (bid % gridDim.x) * TN;

  int aoff[NP][FR], boff[NP][FC];
#pragma unroll
  for (int p = 0; p < NP; ++p) {
#pragma unroll
    for (int m = 0; m < FR; ++m) {
      const int row = wr + m * 16 + (lane & 15);
      const int kga = (lane >> 4) ^ ((row >> 1) & 3);
      aoff[p][m] = (p * 512 + row * 4 + kga) * 8;
    }
#pragma unroll
    for (int n = 0; n < FC; ++n) {
      const int col = wc + n * 16 + (lane & 15);
      const int kgb = (lane >> 4) ^ ((col >> 1) & 3);
      boff[p][n] = (p * BPG + col * 4 + kgb) * 8;
    }
  }

  f32x4 acc[FR][FC];
#pragma unroll
  for (int m = 0; m < FR; ++m)
#pragma unroll
    for (int n = 0; n < FC; ++n) acc[m][n] = (f32x4){0.f, 0.f, 0.f, 0.f};

  for (int k0 = 0; k0 < K; k0 += 32) {
#pragma unroll
    for (int i = 0; i < (NP * (512 + TN * 4)) / 256; ++i) {
      const int g0 = i * 256 + wave * 64;
      const bool isB = g0 >= AG;
      const int ga0 = g0 - (isB ? AG : 0);
      const int ga = ga0 + lane;
      const int pl = isB ? (ga / BPG) : (ga >> 9);
      const int gp = isB ? (ga % BPG) : (ga & 511);
      const int r = gp >> 2;
      const int cg = (gp & 3) ^ ((r >> 1) & 3);
      const f16* gs = (isB ? Bp + (size_t)pl * sBp + (size_t)(bn + r) * K
                           : Ap + (size_t)pl * sAp + (size_t)(bm + r) * K) +
                      k0 + cg * 8;
      f16* ld = (isB ? Bs : As) + (size_t)ga0 * 8;
      gl_lds16(gs, ld);
    }
    __syncthreads();

    half8 af[NP][FR], bf[NP][FC];
#pragma unroll
    for (int p = 0; p < NP; ++p) {
#pragma unroll
      for (int m = 0; m < FR; ++m) af[p][m] = *(const half8*)&As[aoff[p][m]];
#pragma unroll
      for (int n = 0; n < FC; ++n) bf[p][n] = *(const half8*)&Bs[boff[p][n]];
    }
#pragma unroll
    for (int m = 0; m < FR; ++m) {
#pragma unroll
      for (int n = 0; n < FC; ++n) {
        acc[m][n] = __builtin_amdgcn_mfma_f32_16x16x32_f16(af[0][m], bf[0][n],
                                                           acc[m][n], 0, 0, 0);
        if (NP == 2) {
          acc[m][n] = __builtin_amdgcn_mfma_f32_16x16x32_f16(
              af[0][m], bf[1][n], acc[m][n], 0, 0, 0);
          acc[m][n] = __builtin_amdgcn_mfma_f32_16x16x32_f16(
              af[1][m], bf[0][n], acc[m][n], 0, 0, 0);
        }
      }
    }
    __syncthreads();
  }

#pragma unroll
  for (int m = 0; m < FR; ++m) {
#pragma unroll
    for (int n = 0; n < FC; ++n) {
      const int col = bn + wc + n * 16 + (lane & 15);
      const float bv = BIASF ? bias[col] : 0.f;
#pragma unroll
      for (int q = 0; q < 4; ++q) {
        const int row = bm + wr + m * 16 + (lane >> 4) * 4 + q;
        float v = acc[m][n][q] * scale;
        if (EPI == 0) {
          ((float*)Cv)[(size_t)row * N + col] = v + bv;
        } else if (EPI == 1) {
          f16* C = (f16*)Cv;
          const f16 h = (f16)v;
          C[(size_t)row * N + col] = h;
          C[sCp + (size_t)row * N + col] = (f16)(v - (float)h);
        } else {
          ((f16*)Cv)[(size_t)row * N + col] = (f16)v;
        }
      }
    }
  }
}

// fused elementwise splits: X->split2, R->split2, W->split1 (one launch)
__global__ __launch_bounds__(256) void split_fused(
    const float* __restrict__ X, const float* __restrict__ R,
    const float* __restrict__ W, f16* __restrict__ Xp, f16* __restrict__ Rp,
    f16* __restrict__ Wp, long sX, long sR) {
  const int b = blockIdx.x;
  const float* in;
  f16* out;
  long ps;
  int np, i;
  if (b < 4096) {
    in = X; out = Xp; ps = sX; np = 2; i = b * 256 + threadIdx.x;
  } else if (b < 5120) {
    in = R; out = Rp; ps = sR; np = 2; i = (b - 4096) * 256 + threadIdx.x;
  } else {
    in = W; out = Wp; ps = 0; np = 1; i = (b - 5120) * 256 + threadIdx.x;
  }
  const float4 v = ((const float4*)in)[i];
  const float vv[4] = {v.x, v.y, v.z, v.w};
  half4 h, mm;
#pragma unroll
  for (int q = 0; q < 4; ++q) {
    h[q] = (f16)vv[q];
    mm[q] = (f16)(vv[q] - (float)h[q]);
  }
  ((half4*)out)[i] = h;
  if (np == 2) ((half4*)(out + ps))[i] = mm;
}

// fp32 [Mr,Nc] -> 2 fp16 planes of the TRANSPOSE [Nc,Mr]
__global__ __launch_bounds__(256) void split_t2(const float* __restrict__ in,
                                                f16* __restrict__ out, int Mr,
                                                int Nc, long planeStride) {
  __shared__ float Ls[64][65];
  const int i0 = blockIdx.y * 64;
  const int j0 = blockIdx.x * 64;
  const int t = threadIdx.x;
  const int r = t >> 4;
  const int c = (t & 15) * 4;
#pragma unroll
  for (int i = 0; i < 4; ++i) {
    const float4 v =
        *(const float4*)&in[(size_t)(i0 + r + i * 16) * Nc + j0 + c];
    Ls[r + i * 16][c + 0] = v.x;
    Ls[r + i * 16][c + 1] = v.y;
    Ls[r + i * 16][c + 2] = v.z;
    Ls[r + i * 16][c + 3] = v.w;
  }
  __syncthreads();
#pragma unroll
  for (int i = 0; i < 4; ++i) {
    const int r2 = r + i * 16;
    half4 h, mm;
#pragma unroll
    for (int q = 0; q < 4; ++q) {
      const float v = Ls[c + q][r2];
      h[q] = (f16)v;
      mm[q] = (f16)(v - (float)h[q]);
    }
    *(half4*)&out[(size_t)(j0 + r2) * Mr + i0 + c] = h;
    *(half4*)&out[planeStride + (size_t)(j0 + r2) * Mr + i0 + c] = mm;
  }
}

// row softmax over split2-f16 logits [4096] -> f16 P row; one block per row.
__global__ __launch_bounds__(256) void softmax_ps(const f16* __restrict__ Lh,
                                                  long sL,
                                                  f16* __restrict__ P) {
  __shared__ float row[4096];
  __shared__ float red[8];
  const int rix = blockIdx.x;
  const f16* ph = Lh + (size_t)rix * 4096;
  const f16* pm = ph + sL;
  f16* o = P + (size_t)rix * 4096;
  const int tid = threadIdx.x;

  float mx = -INFINITY;
  for (int i = tid * 8; i < 4096; i += 2048) {
    const half8 h = *(const half8*)&ph[i];
    const half8 mseg = *(const half8*)&pm[i];
#pragma unroll
    for (int q = 0; q < 8; ++q) {
      const float v = (float)h[q] + (float)mseg[q];
      row[i + q] = v;
      mx = fmaxf(mx, v);
    }
  }
#pragma unroll
  for (int off = 32; off > 0; off >>= 1) mx = fmaxf(mx, __shfl_xor(mx, off));
  if ((tid & 63) == 0) red[tid >> 6] = mx;
  __syncthreads();
  mx = fmaxf(fmaxf(red[0], red[1]), fmaxf(red[2], red[3]));

  float s = 0.f;
  for (int i = tid * 4; i < 4096; i += 1024) {
    float4 v = *reinterpret_cast<const float4*>(&row[i]);
    v.x = expf(v.x - mx);
    v.y = expf(v.y - mx);
    v.z = expf(v.z - mx);
    v.w = expf(v.w - mx);
    s += v.x + v.y + v.z + v.w;
    *reinterpret_cast<float4*>(&row[i]) = v;
  }
#pragma unroll
  for (int off = 32; off > 0; off >>= 1) s += __shfl_xor(s, off);
  if ((tid & 63) == 0) red[4 + (tid >> 6)] = s;
  __syncthreads();
  s = red[4] + red[5] + red[6] + red[7];
  const float inv = 1.0f / s;

  for (int i = tid * 8; i < 4096; i += 2048) {
    half8 h;
#pragma unroll
    for (int q = 0; q < 8; ++q) h[q] = (f16)(row[i + q] * inv);
    *(half8*)&o[i] = h;
  }
}

extern "C" void kernel_launch(void* const* d_in, const int* in_sizes, int n_in,
                              void* d_out, int out_size, void* d_ws,
                              size_t ws_size, hipStream_t stream) {
  const float* X = (const float*)d_in[0];   // [4096,1024]
  const float* R = (const float*)d_in[1];   // [1024,1024]
  const float* Wl = (const float*)d_in[2];  // [1024,1024] (out,in)
  const float* bias = (const float*)d_in[3];
  float* out = (float*)d_out;

  const int Bq = 4096, D = 1024;
  const size_t MiB = 1 << 20;
  uint8_t* w8 = (uint8_t*)d_ws;
  // Layout (live-range checked):
  //  Xp [0,16) split2 X           (dead after G4; Pp overwrites)
  //  Tp [16,32) split2 T          (dead after G4)
  //  Yt [32,40) f16 (X W^T)^T     (live until G5)
  //  Wp [40,42) f16 W             (dead after G3)
  //  Rp [42,46) Rtp [46,50) Mtp [50,54)  (dead after G2)
  //  Lh [54,70) Lm [70,86) split2 logits (dead after softmax)
  //  Pp [0,32)  f16 P             (written by softmax, read by G5)
  f16* Xp = (f16*)(w8);
  f16* Tp = (f16*)(w8 + 16 * MiB);
  f16* Yt = (f16*)(w8 + 32 * MiB);
  f16* Wp = (f16*)(w8 + 40 * MiB);
  f16* Rp = (f16*)(w8 + 42 * MiB);
  f16* Rtp = (f16*)(w8 + 46 * MiB);
  f16* Mtp = (f16*)(w8 + 50 * MiB);
  f16* Lh = (f16*)(w8 + 54 * MiB);
  f16* Pp = (f16*)(w8);

  const long sR = (long)D * D, sX = (long)Bq * D;
  const long sL = (long)Bq * Bq;
  const dim3 blk(256), blk512(512);

  // fused elementwise splits (X, R, W) + R-transpose split
  split_fused<<<dim3(6144), blk, 0, stream>>>(X, R, Wl, Xp, Rp, Wp, sX, sR);
  split_t2<<<dim3(D / 64, D / 64), blk, 0, stream>>>(R, Rtp, D, D, sR);

  // G1: Mt = Rt . R^T  (split2 out), grid 128
  gemm_mp<2, 64, 1, false, 2><<<dim3(D / 64, D / 128), blk, 0, stream>>>(
      Rtp, Rp, Mtp, nullptr, D, D, D, sR, sR, sR, 1.f);
  // G3: Yt = Wp . (Xp h-plane)^T = (X W^T)^T  (f16), dp, grid 256
  gemm_dp<1, 2, false><<<dim3(Bq / 128, D / 128), blk512, 0, stream>>>(
      Wp, Xp, Yt, nullptr, D, Bq, D, 0, 0, 0, 1.f);
  // G2: T = Xp . Mt^T  (split2 out), dp, grid 256
  gemm_dp<2, 1, false><<<dim3(D / 128, Bq / 128), blk512, 0, stream>>>(
      Xp, Mtp, Tp, nullptr, Bq, D, D, sX, sR, sX, 1.f);
  // G4: L = scale * Tp . Xp^T  (split2-f16 out), q2 body, grid 256
  gemm_q2<<<dim3(Bq / 256, Bq / 256), blk512, 0, stream>>>(
      Tp, Xp, Lh, sL, Bq, D, sX, sX, 0.03125f);
  // softmax rows (h+m combine) -> f16 P (overwrites Xp/Tp)
  softmax_ps<<<dim3(Bq), blk, 0, stream>>>(Lh, sL, Pp);
  // G5: out = Pp . Yt^T + bias  (fp32), dp, grid 256
  gemm_dp<1, 0, true><<<dim3(D / 128, Bq / 128), blk512, 0, stream>>>(
      Pp, Yt, out, bias, Bq, D, Bq, 0, 0, 0, 1.f);
}

// Round 11
// 225.768 us; speedup vs baseline: 1.7884x; 1.0121x over previous
//
#include <hip/hip_runtime.h>
#include <math.h>
#include <stdint.h>

using f16 = _Float16;
using half8 = __attribute__((ext_vector_type(8))) f16;
using half4 = __attribute__((ext_vector_type(4))) f16;
using f32x4 = __attribute__((ext_vector_type(4))) float;

__device__ __forceinline__ void gl_lds16(const f16* g, f16* l) {
  __builtin_amdgcn_global_load_lds(
      (const __attribute__((address_space(1))) void*)g,
      (__attribute__((address_space(3))) void*)l, 16, 0, 0);
}

// ---------------------------------------------------------------------------
// 256^2-tile Markidis GEMM (round-9 q2 body — best measured: ~100us,
// MfmaUtil 46.6, FETCH 74MB). Barrier-free inner tile, full drain at tile top
// (drain doubles as inter-block k-sync preserving L2 panel sharing; counted
// vmcnt desyncs blocks and triples HBM fetch — round 8). Staging split 4+4:
// first half with Q1 frag reads, second half after Q2 MFMA (round-10 burst
// variant regressed). Epilogue: split2-f16 planes.
// ---------------------------------------------------------------------------
__global__ __launch_bounds__(512, 2) void gemm_q2(
    const f16* __restrict__ Ap, const f16* __restrict__ Bp,
    f16* __restrict__ Ch, long sCp, int N, int K, long sAp, long sBp,
    float scale) {
  __shared__ f16 lds[2 * 4096 * 8];
  const int tid = threadIdx.x;
  const int lane = tid & 63;
  const int wave = tid >> 6;
  const int wr = (wave >> 2) * 128;
  const int wc = (wave & 3) * 64;

  const int nwg = gridDim.x * gridDim.y;
  int bid = blockIdx.y * gridDim.x + blockIdx.x;
  bid = (bid & 7) * (nwg >> 3) + (bid >> 3);  // XCD-aware (nwg % 8 == 0)
  const int bm = (bid / gridDim.x) * 256;
  const int bn = (bid % gridDim.x) * 256;

  const int nt = K / 32;

  auto stage = [&](int t, int i) {
    const int g0 = i * 512 + wave * 64;  // wave-uniform granule base
    const int ga = g0 + lane;
    const bool isB = ga >= 2048;
    const int gl = ga & 2047;
    const int pl = gl >> 10;
    const int gp = gl & 1023;
    const int r = gp >> 2;
    const int cg = (gp & 3) ^ ((r >> 1) & 3);  // XOR-swizzled source granule
    const f16* gs = (isB ? Bp + (size_t)pl * sBp + (size_t)(bn + r) * K
                         : Ap + (size_t)pl * sAp + (size_t)(bm + r) * K) +
                    t * 32 + cg * 8;
    gl_lds16(gs, &lds[((size_t)(t & 1) * 4096 + g0) * 8]);
  };

  int aoff[2][8], boff[2][4];
#pragma unroll
  for (int pl = 0; pl < 2; ++pl) {
#pragma unroll
    for (int fr = 0; fr < 8; ++fr) {
      const int row = wr + fr * 16 + (lane & 15);
      const int kg = (lane >> 4) ^ ((row >> 1) & 3);
      aoff[pl][fr] = (pl * 1024 + row * 4 + kg) * 8;
    }
#pragma unroll
    for (int fc = 0; fc < 4; ++fc) {
      const int col = wc + fc * 16 + (lane & 15);
      const int kg = (lane >> 4) ^ ((col >> 1) & 3);
      boff[pl][fc] = (2048 + pl * 1024 + col * 4 + kg) * 8;
    }
  }

  f32x4 acc[8][4];
#pragma unroll
  for (int m = 0; m < 8; ++m)
#pragma unroll
    for (int n = 0; n < 4; ++n) acc[m][n] = (f32x4){0.f, 0.f, 0.f, 0.f};

  half8 af0[2][4], af1[2][4], bf0[2][2], bf1[2][2];

#define LOAD_A(dst, h)                                          \
  _Pragma("unroll") for (int pl = 0; pl < 2; ++pl)              \
      _Pragma("unroll") for (int i = 0; i < 4; ++i) dst[pl][i] = \
          *(const half8*)&buf[aoff[pl][(h) * 4 + i]];
#define LOAD_B(dst, h)                                          \
  _Pragma("unroll") for (int pl = 0; pl < 2; ++pl)              \
      _Pragma("unroll") for (int j = 0; j < 2; ++j) dst[pl][j] = \
          *(const half8*)&buf[boff[pl][(h) * 2 + j]];
#define MFMA_Q(A, B, ah, bh)                                                  \
  _Pragma("unroll") for (int i = 0; i < 4; ++i)                               \
      _Pragma("unroll") for (int j = 0; j < 2; ++j) {                         \
    f32x4& c = acc[(ah) * 4 + i][(bh) * 2 + j];                               \
    c = __builtin_amdgcn_mfma_f32_16x16x32_f16(A[0][i], B[0][j], c, 0, 0, 0); \
    c = __builtin_amdgcn_mfma_f32_16x16x32_f16(A[0][i], B[1][j], c, 0, 0, 0); \
    c = __builtin_amdgcn_mfma_f32_16x16x32_f16(A[1][i], B[0][j], c, 0, 0, 0); \
  }
#define SBAR0() __builtin_amdgcn_sched_barrier(0)

  // prologue: prime tile 0
#pragma unroll
  for (int i = 0; i < 8; ++i) stage(0, i);

  for (int t = 0; t < nt; ++t) {
    const f16* buf = &lds[(size_t)(t & 1) * 4096 * 8];
    asm volatile("s_waitcnt vmcnt(0)" ::: "memory");
    asm volatile("s_barrier" ::: "memory");
    const bool pf = (t + 1 < nt);

    // issue Q1 frags + first half of next-tile staging
    LOAD_A(af0, 0);
    LOAD_B(bf0, 0);
    if (pf) { stage(t + 1, 0); stage(t + 1, 1); stage(t + 1, 2); stage(t + 1, 3); }
    SBAR0();
    LOAD_B(bf1, 1);  // prefetch Q2 frags
    SBAR0();
    __builtin_amdgcn_s_setprio(1);
    MFMA_Q(af0, bf0, 0, 0);
    __builtin_amdgcn_s_setprio(0);
    SBAR0();
    LOAD_A(af1, 1);  // prefetch Q3/Q4 A-frags
    if (pf) { stage(t + 1, 4); stage(t + 1, 5); stage(t + 1, 6); stage(t + 1, 7); }
    SBAR0();
    __builtin_amdgcn_s_setprio(1);
    MFMA_Q(af0, bf1, 0, 1);
    __builtin_amdgcn_s_setprio(0);
    SBAR0();
    LOAD_B(bf0, 0);  // re-read B0 for Q4 (keeps peak live frags low)
    SBAR0();
    __builtin_amdgcn_s_setprio(1);
    MFMA_Q(af1, bf1, 1, 1);
    __builtin_amdgcn_s_setprio(0);
    SBAR0();
    __builtin_amdgcn_s_setprio(1);
    MFMA_Q(af1, bf0, 1, 0);
    __builtin_amdgcn_s_setprio(0);
    SBAR0();
  }
#undef LOAD_A
#undef LOAD_B
#undef MFMA_Q
#undef SBAR0

  // epilogue: split2-f16 planes. C/D layout: col = lane&15, row = (lane>>4)*4+q
#pragma unroll
  for (int m = 0; m < 8; ++m) {
#pragma unroll
    for (int n = 0; n < 4; ++n) {
      const int col = bn + wc + n * 16 + (lane & 15);
#pragma unroll
      for (int q = 0; q < 4; ++q) {
        const int row = bm + wr + m * 16 + (lane >> 4) * 4 + q;
        const float v = acc[m][n][q] * scale;
        const f16 h = (f16)v;
        Ch[(size_t)row * N + col] = h;
        Ch[sCp + (size_t)row * N + col] = (f16)(v - (float)h);
      }
    }
  }
}

// ---------------------------------------------------------------------------
// 128^2 deep-pipelined GEMM, barrier-free inner tile (round 10, kept): one
// barrier + one counted vmcnt per K-tile; all 12 frag reads issued together;
// compiler counted-lgkm interleaves reads with MFMAs. Mod-3 buffer rotation
// makes reads(buf t) vs writes(buf t+2) collision-free.
// ---------------------------------------------------------------------------
template <int NP, int EPI, bool BIASF>
__global__ __launch_bounds__(512, 2) void gemm_dp(
    const f16* __restrict__ Ap, const f16* __restrict__ Bp,
    void* __restrict__ Cv, const float* __restrict__ bias, int M, int N, int K,
    long sAp, long sBp, long sCp, float scale) {
  __shared__ f16 lds[3 * 2048 * 8];
  const int tid = threadIdx.x;
  const int lane = tid & 63;
  const int wave = tid >> 6;
  const int wr = (wave >> 1) * 32;
  const int wc = (wave & 1) * 64;

  const int nwg = gridDim.x * gridDim.y;
  int bid = blockIdx.y * gridDim.x + blockIdx.x;
  bid = (bid & 7) * (nwg >> 3) + (bid >> 3);
  const int bm = (bid / gridDim.x) * 128;
  const int bn = (bid % gridDim.x) * 128;

  constexpr int KSTEP = (NP == 2) ? 32 : 64;
  const int nt = K / KSTEP;

  auto stage = [&](int t, int i) {
    const int g0 = i * 512 + wave * 64;
    const int ga = g0 + lane;
    const bool isB = ga >= 1024;
    const int gl = ga & 1023;
    const int pl = gl >> 9;
    const int gp = gl & 511;
    const int r = gp >> 2;
    const int cg = (gp & 3) ^ ((r >> 1) & 3);
    const long sP = (NP == 2) ? (isB ? sBp : sAp) : 0;
    const int kOff = (NP == 2) ? 0 : pl * 32;
    const f16* gs = (isB ? Bp : Ap) + (size_t)pl * sP +
                    (size_t)((isB ? bn : bm) + r) * K + t * KSTEP + kOff +
                    cg * 8;
    gl_lds16(gs, &lds[((size_t)(t % 3) * 2048 + g0) * 8]);
  };

  int aoff[2][2], boff[2][4];
#pragma unroll
  for (int pl = 0; pl < 2; ++pl) {
#pragma unroll
    for (int m = 0; m < 2; ++m) {
      const int row = wr + m * 16 + (lane & 15);
      const int kg = (lane >> 4) ^ ((row >> 1) & 3);
      aoff[pl][m] = (pl * 512 + row * 4 + kg) * 8;
    }
#pragma unroll
    for (int n = 0; n < 4; ++n) {
      const int col = wc + n * 16 + (lane & 15);
      const int kg = (lane >> 4) ^ ((col >> 1) & 3);
      boff[pl][n] = (1024 + pl * 512 + col * 4 + kg) * 8;
    }
  }

  f32x4 acc[2][4];
#pragma unroll
  for (int m = 0; m < 2; ++m)
#pragma unroll
    for (int n = 0; n < 4; ++n) acc[m][n] = (f32x4){0.f, 0.f, 0.f, 0.f};

#pragma unroll
  for (int i = 0; i < 4; ++i) stage(0, i);
#pragma unroll
  for (int i = 0; i < 4; ++i) stage(1, i);

  for (int t = 0; t < nt; ++t) {
    const f16* buf = &lds[(size_t)(t % 3) * 2048 * 8];
    if (t + 1 < nt)
      asm volatile("s_waitcnt vmcnt(4)" ::: "memory");
    else
      asm volatile("s_waitcnt vmcnt(0)" ::: "memory");
    asm volatile("s_barrier" ::: "memory");

    half8 af[2][2], bf[2][4];
#pragma unroll
    for (int pl = 0; pl < 2; ++pl) {
#pragma unroll
      for (int m = 0; m < 2; ++m) af[pl][m] = *(const half8*)&buf[aoff[pl][m]];
#pragma unroll
      for (int n = 0; n < 4; ++n) bf[pl][n] = *(const half8*)&buf[boff[pl][n]];
    }
    if (t + 2 < nt) {
      stage(t + 2, 0);
      stage(t + 2, 1);
      stage(t + 2, 2);
      stage(t + 2, 3);
    }
    __builtin_amdgcn_sched_barrier(0);
    __builtin_amdgcn_s_setprio(1);
#pragma unroll
    for (int m = 0; m < 2; ++m) {
#pragma unroll
      for (int n = 0; n < 4; ++n) {
        acc[m][n] = __builtin_amdgcn_mfma_f32_16x16x32_f16(af[0][m], bf[0][n],
                                                           acc[m][n], 0, 0, 0);
        if (NP == 2) {
          acc[m][n] = __builtin_amdgcn_mfma_f32_16x16x32_f16(
              af[0][m], bf[1][n], acc[m][n], 0, 0, 0);
          acc[m][n] = __builtin_amdgcn_mfma_f32_16x16x32_f16(
              af[1][m], bf[0][n], acc[m][n], 0, 0, 0);
        } else {
          acc[m][n] = __builtin_amdgcn_mfma_f32_16x16x32_f16(
              af[1][m], bf[1][n], acc[m][n], 0, 0, 0);
        }
      }
    }
    __builtin_amdgcn_s_setprio(0);
    __builtin_amdgcn_sched_barrier(0);
  }

#pragma unroll
  for (int m = 0; m < 2; ++m) {
#pragma unroll
    for (int n = 0; n < 4; ++n) {
      const int col = bn + wc + n * 16 + (lane & 15);
      const float bv = BIASF ? bias[col] : 0.f;
#pragma unroll
      for (int q = 0; q < 4; ++q) {
        const int row = bm + wr + m * 16 + (lane >> 4) * 4 + q;
        float v = acc[m][n][q] * scale;
        if (EPI == 0) {
          ((float*)Cv)[(size_t)row * N + col] = v + bv;
        } else if (EPI == 1) {
          f16* C = (f16*)Cv;
          const f16 h = (f16)v;
          C[(size_t)row * N + col] = h;
          C[sCp + (size_t)row * N + col] = (f16)(v - (float)h);
        } else {
          ((f16*)Cv)[(size_t)row * N + col] = (f16)v;
        }
      }
    }
  }
}

// ---------------------------------------------------------------------------
// Round-3 2-barrier kernel, kept for the tiny G1 (grid 128)
// ---------------------------------------------------------------------------
template <int NP, int TN, int EPI, bool BIASF, int MINW>
__global__ __launch_bounds__(256, MINW) void gemm_mp(
    const f16* __restrict__ Ap, const f16* __restrict__ Bp,
    void* __restrict__ Cv, const float* __restrict__ bias, int M, int N, int K,
    long sAp, long sBp, long sCp, float scale) {
  constexpr int FR = (TN == 128) ? 4 : 2;
  constexpr int FC = 4;
  constexpr int AG = NP * 512;
  constexpr int BPG = TN * 4;
  __shared__ f16 As[NP * 128 * 32];
  __shared__ f16 Bs[NP * TN * 32];
  const int tid = threadIdx.x;
  const int lane = tid & 63;
  const int wave = tid >> 6;
  const int wr = (TN == 128) ? (wave >> 1) * 64 : wave * 32;
  const int wc = (TN == 128) ? (wave & 1) * 64 : 0;

  const int nwg = gridDim.x * gridDim.y;
  int bid = blockIdx.y * gridDim.x + blockIdx.x;
  bid = (bid & 7) * (nwg >> 3) + (bid >> 3);
  const int bm = (bid / gridDim.x) * 128;
  const int bn = (bid % gridDim.x) * TN;

  int aoff[NP][FR], boff[NP][FC];
#pragma unroll
  for (int p = 0; p < NP; ++p) {
#pragma unroll
    for (int m = 0; m < FR; ++m) {
      const int row = wr + m * 16 + (lane & 15);
      const int kga = (lane >> 4) ^ ((row >> 1) & 3);
      aoff[p][m] = (p * 512 + row * 4 + kga) * 8;
    }
#pragma unroll
    for (int n = 0; n < FC; ++n) {
      const int col = wc + n * 16 + (lane & 15);
      const int kgb = (lane >> 4) ^ ((col >> 1) & 3);
      boff[p][n] = (p * BPG + col * 4 + kgb) * 8;
    }
  }

  f32x4 acc[FR][FC];
#pragma unroll
  for (int m = 0; m < FR; ++m)
#pragma unroll
    for (int n = 0; n < FC; ++n) acc[m][n] = (f32x4){0.f, 0.f, 0.f, 0.f};

  for (int k0 = 0; k0 < K; k0 += 32) {
#pragma unroll
    for (int i = 0; i < (NP * (512 + TN * 4)) / 256; ++i) {
      const int g0 = i * 256 + wave * 64;
      const bool isB = g0 >= AG;
      const int ga0 = g0 - (isB ? AG : 0);
      const int ga = ga0 + lane;
      const int pl = isB ? (ga / BPG) : (ga >> 9);
      const int gp = isB ? (ga % BPG) : (ga & 511);
      const int r = gp >> 2;
      const int cg = (gp & 3) ^ ((r >> 1) & 3);
      const f16* gs = (isB ? Bp + (size_t)pl * sBp + (size_t)(bn + r) * K
                           : Ap + (size_t)pl * sAp + (size_t)(bm + r) * K) +
                      k0 + cg * 8;
      f16* ld = (isB ? Bs : As) + (size_t)ga0 * 8;
      gl_lds16(gs, ld);
    }
    __syncthreads();

    half8 af[NP][FR], bf[NP][FC];
#pragma unroll
    for (int p = 0; p < NP; ++p) {
#pragma unroll
      for (int m = 0; m < FR; ++m) af[p][m] = *(const half8*)&As[aoff[p][m]];
#pragma unroll
      for (int n = 0; n < FC; ++n) bf[p][n] = *(const half8*)&Bs[boff[p][n]];
    }
#pragma unroll
    for (int m = 0; m < FR; ++m) {
#pragma unroll
      for (int n = 0; n < FC; ++n) {
        acc[m][n] = __builtin_amdgcn_mfma_f32_16x16x32_f16(af[0][m], bf[0][n],
                                                           acc[m][n], 0, 0, 0);
        if (NP == 2) {
          acc[m][n] = __builtin_amdgcn_mfma_f32_16x16x32_f16(
              af[0][m], bf[1][n], acc[m][n], 0, 0, 0);
          acc[m][n] = __builtin_amdgcn_mfma_f32_16x16x32_f16(
              af[1][m], bf[0][n], acc[m][n], 0, 0, 0);
        }
      }
    }
    __syncthreads();
  }

#pragma unroll
  for (int m = 0; m < FR; ++m) {
#pragma unroll
    for (int n = 0; n < FC; ++n) {
      const int col = bn + wc + n * 16 + (lane & 15);
      const float bv = BIASF ? bias[col] : 0.f;
#pragma unroll
      for (int q = 0; q < 4; ++q) {
        const int row = bm + wr + m * 16 + (lane >> 4) * 4 + q;
        float v = acc[m][n][q] * scale;
        if (EPI == 0) {
          ((float*)Cv)[(size_t)row * N + col] = v + bv;
        } else if (EPI == 1) {
          f16* C = (f16*)Cv;
          const f16 h = (f16)v;
          C[(size_t)row * N + col] = h;
          C[sCp + (size_t)row * N + col] = (f16)(v - (float)h);
        } else {
          ((f16*)Cv)[(size_t)row * N + col] = (f16)v;
        }
      }
    }
  }
}

// fused elementwise splits: X->split2, R->split2, W->split1 (one launch)
__global__ __launch_bounds__(256) void split_fused(
    const float* __restrict__ X, const float* __restrict__ R,
    const float* __restrict__ W, f16* __restrict__ Xp, f16* __restrict__ Rp,
    f16* __restrict__ Wp, long sX, long sR) {
  const int b = blockIdx.x;
  const float* in;
  f16* out;
  long ps;
  int np, i;
  if (b < 4096) {
    in = X; out = Xp; ps = sX; np = 2; i = b * 256 + threadIdx.x;
  } else if (b < 5120) {
    in = R; out = Rp; ps = sR; np = 2; i = (b - 4096) * 256 + threadIdx.x;
  } else {
    in = W; out = Wp; ps = 0; np = 1; i = (b - 5120) * 256 + threadIdx.x;
  }
  const float4 v = ((const float4*)in)[i];
  const float vv[4] = {v.x, v.y, v.z, v.w};
  half4 h, mm;
#pragma unroll
  for (int q = 0; q < 4; ++q) {
    h[q] = (f16)vv[q];
    mm[q] = (f16)(vv[q] - (float)h[q]);
  }
  ((half4*)out)[i] = h;
  if (np == 2) ((half4*)(out + ps))[i] = mm;
}

// fp32 [Mr,Nc] -> 2 fp16 planes of the TRANSPOSE [Nc,Mr]
__global__ __launch_bounds__(256) void split_t2(const float* __restrict__ in,
                                                f16* __restrict__ out, int Mr,
                                                int Nc, long planeStride) {
  __shared__ float Ls[64][65];
  const int i0 = blockIdx.y * 64;
  const int j0 = blockIdx.x * 64;
  const int t = threadIdx.x;
  const int r = t >> 4;
  const int c = (t & 15) * 4;
#pragma unroll
  for (int i = 0; i < 4; ++i) {
    const float4 v =
        *(const float4*)&in[(size_t)(i0 + r + i * 16) * Nc + j0 + c];
    Ls[r + i * 16][c + 0] = v.x;
    Ls[r + i * 16][c + 1] = v.y;
    Ls[r + i * 16][c + 2] = v.z;
    Ls[r + i * 16][c + 3] = v.w;
  }
  __syncthreads();
#pragma unroll
  for (int i = 0; i < 4; ++i) {
    const int r2 = r + i * 16;
    half4 h, mm;
#pragma unroll
    for (int q = 0; q < 4; ++q) {
      const float v = Ls[c + q][r2];
      h[q] = (f16)v;
      mm[q] = (f16)(v - (float)h[q]);
    }
    *(half4*)&out[(size_t)(j0 + r2) * Mr + i0 + c] = h;
    *(half4*)&out[planeStride + (size_t)(j0 + r2) * Mr + i0 + c] = mm;
  }
}

// row softmax over split2-f16 logits [4096] -> f16 P row; one block per row.
__global__ __launch_bounds__(256) void softmax_ps(const f16* __restrict__ Lh,
                                                  long sL,
                                                  f16* __restrict__ P) {
  __shared__ float row[4096];
  __shared__ float red[8];
  const int rix = blockIdx.x;
  const f16* ph = Lh + (size_t)rix * 4096;
  const f16* pm = ph + sL;
  f16* o = P + (size_t)rix * 4096;
  const int tid = threadIdx.x;

  float mx = -INFINITY;
  for (int i = tid * 8; i < 4096; i += 2048) {
    const half8 h = *(const half8*)&ph[i];
    const half8 mseg = *(const half8*)&pm[i];
#pragma unroll
    for (int q = 0; q < 8; ++q) {
      const float v = (float)h[q] + (float)mseg[q];
      row[i + q] = v;
      mx = fmaxf(mx, v);
    }
  }
#pragma unroll
  for (int off = 32; off > 0; off >>= 1) mx = fmaxf(mx, __shfl_xor(mx, off));
  if ((tid & 63) == 0) red[tid >> 6] = mx;
  __syncthreads();
  mx = fmaxf(fmaxf(red[0], red[1]), fmaxf(red[2], red[3]));

  float s = 0.f;
  for (int i = tid * 4; i < 4096; i += 1024) {
    float4 v = *reinterpret_cast<const float4*>(&row[i]);
    v.x = expf(v.x - mx);
    v.y = expf(v.y - mx);
    v.z = expf(v.z - mx);
    v.w = expf(v.w - mx);
    s += v.x + v.y + v.z + v.w;
    *reinterpret_cast<float4*>(&row[i]) = v;
  }
#pragma unroll
  for (int off = 32; off > 0; off >>= 1) s += __shfl_xor(s, off);
  if ((tid & 63) == 0) red[4 + (tid >> 6)] = s;
  __syncthreads();
  s = red[4] + red[5] + red[6] + red[7];
  const float inv = 1.0f / s;

  for (int i = tid * 8; i < 4096; i += 2048) {
    half8 h;
#pragma unroll
    for (int q = 0; q < 8; ++q) h[q] = (f16)(row[i + q] * inv);
    *(half8*)&o[i] = h;
  }
}

extern "C" void kernel_launch(void* const* d_in, const int* in_sizes, int n_in,
                              void* d_out, int out_size, void* d_ws,
                              size_t ws_size, hipStream_t stream) {
  const float* X = (const float*)d_in[0];   // [4096,1024]
  const float* R = (const float*)d_in[1];   // [1024,1024]
  const float* Wl = (const float*)d_in[2];  // [1024,1024] (out,in)
  const float* bias = (const float*)d_in[3];
  float* out = (float*)d_out;

  const int Bq = 4096, D = 1024;
  const size_t MiB = 1 << 20;
  uint8_t* w8 = (uint8_t*)d_ws;
  // Layout (live-range checked):
  //  Xp [0,16) split2 X           (dead after G4; Pp overwrites)
  //  Tp [16,32) split2 T          (dead after G4)
  //  Yt [32,40) f16 (X W^T)^T     (live until G5)
  //  Wp [40,42) f16 W             (dead after G3)
  //  Rp [42,46) Rtp [46,50) Mtp [50,54)  (dead after G2)
  //  Lh [54,70) Lm [70,86) split2 logits (dead after softmax)
  //  Pp [0,32)  f16 P             (written by softmax, read by G5)
  f16* Xp = (f16*)(w8);
  f16* Tp = (f16*)(w8 + 16 * MiB);
  f16* Yt = (f16*)(w8 + 32 * MiB);
  f16* Wp = (f16*)(w8 + 40 * MiB);
  f16* Rp = (f16*)(w8 + 42 * MiB);
  f16* Rtp = (f16*)(w8 + 46 * MiB);
  f16* Mtp = (f16*)(w8 + 50 * MiB);
  f16* Lh = (f16*)(w8 + 54 * MiB);
  f16* Pp = (f16*)(w8);

  const long sR = (long)D * D, sX = (long)Bq * D;
  const long sL = (long)Bq * Bq;
  const dim3 blk(256), blk512(512);

  // fused elementwise splits (X, R, W) + R-transpose split
  split_fused<<<dim3(6144), blk, 0, stream>>>(X, R, Wl, Xp, Rp, Wp, sX, sR);
  split_t2<<<dim3(D / 64, D / 64), blk, 0, stream>>>(R, Rtp, D, D, sR);

  // G1: Mt = Rt . R^T  (split2 out), grid 128
  gemm_mp<2, 64, 1, false, 2><<<dim3(D / 64, D / 128), blk, 0, stream>>>(
      Rtp, Rp, Mtp, nullptr, D, D, D, sR, sR, sR, 1.f);
  // G3: Yt = Wp . (Xp h-plane)^T = (X W^T)^T  (f16), dp, grid 256
  gemm_dp<1, 2, false><<<dim3(Bq / 128, D / 128), blk512, 0, stream>>>(
      Wp, Xp, Yt, nullptr, D, Bq, D, 0, 0, 0, 1.f);
  // G2: T = Xp . Mt^T  (split2 out), dp, grid 256
  gemm_dp<2, 1, false><<<dim3(D / 128, Bq / 128), blk512, 0, stream>>>(
      Xp, Mtp, Tp, nullptr, Bq, D, D, sX, sR, sX, 1.f);
  // G4: L = scale * Tp . Xp^T  (split2-f16 out), q2 round-9 body, grid 256
  gemm_q2<<<dim3(Bq / 256, Bq / 256), blk512, 0, stream>>>(
      Tp, Xp, Lh, sL, Bq, D, sX, sX, 0.03125f);
  // softmax rows (h+m combine) -> f16 P (overwrites Xp/Tp)
  softmax_ps<<<dim3(Bq), blk, 0, stream>>>(Lh, sL, Pp);
  // G5: out = Pp . Yt^T + bias  (fp32), dp, grid 256
  gemm_dp<1, 0, true><<<dim3(D / 128, Bq / 128), blk512, 0, stream>>>(
      Pp, Yt, out, bias, Bq, D, Bq, 0, 0, 0, 1.f);
}